// Round 4
// baseline (1598.664 us; speedup 1.0000x reference)
//
#include <hip/hip_runtime.h>
#include <math.h>

#define NN 100000
#define NE 6400000
#define INCH 128
#define BSH 7                    // bucket = 128 dst nodes
#define BW (1 << BSH)
#define NBKT ((NN + BW - 1) / BW)   // 782
#define BCAP 9216                // slots per bucket (mean 8192, +11 sigma)
#define BIN_CH 16384             // edges per bin block

// ---------------- Binning: coarse bucket sort by dst>>7 ---------------------
// Entry packing: (src << 7) | (dst & 127)  -- 24 bits used.
__global__ __launch_bounds__(256) void k_bin(const int* __restrict__ ei,
                                             int* __restrict__ bcnt,
                                             unsigned int* __restrict__ pairs) {
  __shared__ int cnt[NBKT];
  __shared__ int base[NBKT];
  int t = threadIdx.x;
  for (int i = t; i < NBKT; i += 256) cnt[i] = 0;
  __syncthreads();
  int c0 = blockIdx.x * BIN_CH;
  int c1 = c0 + BIN_CH < NE ? c0 + BIN_CH : NE;
  // pass A: histogram (dst only)
  for (int i = c0 + t; i < c1; i += 256) {
    int d = ei[NE + i];
    atomicAdd(&cnt[d >> BSH], 1);
  }
  __syncthreads();
  // reserve global space per bucket
  for (int b = t; b < NBKT; b += 256) {
    int c = cnt[b];
    base[b] = c > 0 ? atomicAdd(&bcnt[b], c) : 0;
    cnt[b] = 0;
  }
  __syncthreads();
  // pass B: re-read chunk (L2-hot), append packed entries
  for (int i = c0 + t; i < c1; i += 256) {
    int s = ei[i], d = ei[NE + i];
    int bkt = d >> BSH;
    int off = atomicAdd(&cnt[bkt], 1);
    int pos = base[bkt] + off;
    if (pos < BCAP)
      pairs[(size_t)bkt * BCAP + pos] = ((unsigned int)s << BSH) | (d & (BW - 1));
  }
}

// ---------------- Layer 1 node: h1 = x@W1; logits embedded in row -----------
// h1 row (stride 16): [h0..h9, as_x, as_y, pad x4]; ad1 separate.
__global__ __launch_bounds__(256) void k_l1_node(
    const float* __restrict__ x, const float* __restrict__ W1,
    const float* __restrict__ a_src1, const float* __restrict__ a_dst1,
    float* __restrict__ h1, float2* __restrict__ ad1) {
  __shared__ float Wt[10 * INCH];
  __shared__ float asw[10], adw[10];
  for (int i = threadIdx.x; i < 10 * INCH; i += blockDim.x) {
    int c = i / 10, k = i - c * 10;
    Wt[k * INCH + c] = W1[i];
  }
  if (threadIdx.x < 10) {
    asw[threadIdx.x] = a_src1[threadIdx.x];
    adw[threadIdx.x] = a_dst1[threadIdx.x];
  }
  __syncthreads();
  int n = blockIdx.x * blockDim.x + threadIdx.x;
  if (n >= NN) return;
  const float4* xr = (const float4*)(x + (size_t)n * INCH);
  const float4* Wt4 = (const float4*)Wt;
  float acc[10];
#pragma unroll
  for (int k = 0; k < 10; k++) acc[k] = 0.f;
#pragma unroll 8
  for (int c4 = 0; c4 < INCH / 4; c4++) {
    float4 xv = xr[c4];
#pragma unroll
    for (int k = 0; k < 10; k++) {
      float4 wv = Wt4[k * (INCH / 4) + c4];
      acc[k] += xv.x * wv.x + xv.y * wv.y + xv.z * wv.z + xv.w * wv.w;
    }
  }
  float s0 = 0.f, s1 = 0.f, d0 = 0.f, d1 = 0.f;
#pragma unroll
  for (int j = 0; j < 5; j++) {
    s0 += acc[j] * asw[j];
    s1 += acc[5 + j] * asw[5 + j];
    d0 += acc[j] * adw[j];
    d1 += acc[5 + j] * adw[5 + j];
  }
  float4* hrow = (float4*)(h1 + (size_t)n * 16);
  hrow[0] = make_float4(acc[0], acc[1], acc[2], acc[3]);
  hrow[1] = make_float4(acc[4], acc[5], acc[6], acc[7]);
  hrow[2] = make_float4(acc[8], acc[9], s0, s1);
  ad1[n] = make_float2(d0, d1);
}

// ------- Layer 1 aggregation: one block per bucket, LDS accumulation --------
__global__ __launch_bounds__(256) void k_l1_aggb(
    const int* __restrict__ bcnt, const unsigned int* __restrict__ pairs,
    const float* __restrict__ h1, const float2* __restrict__ ad1,
    const float* __restrict__ b1, float* __restrict__ g1) {
  __shared__ float acc[BW * 13];  // per node: num0..9, den0, den1 (stride 13)
  __shared__ float2 adw[BW];
  int t = threadIdx.x;
  int b = blockIdx.x;
  int base_n = b << BSH;
  int nloc = NN - base_n < BW ? NN - base_n : BW;
  for (int i = t; i < BW * 13; i += 256) acc[i] = 0.f;
  if (t < BW) adw[t] = (t < nloc) ? ad1[base_n + t] : make_float2(0.f, 0.f);
  __syncthreads();
  int cntb = bcnt[b];
  cntb = cntb > BCAP ? BCAP : cntb;
  const unsigned int* pp = pairs + (size_t)b * BCAP;
  for (int k = t; k < cntb; k += 256) {
    unsigned int e = pp[k];
    int dl = e & (BW - 1);
    int s = e >> BSH;
    const float4* hs = (const float4*)(h1 + (size_t)s * 16);
    float4 r0 = hs[0], r1 = hs[1], r2 = hs[2];
    float2 adn = adw[dl];
    float e0 = r2.z + adn.x; e0 = e0 > 0.f ? e0 : 0.2f * e0;
    float e1 = r2.w + adn.y; e1 = e1 > 0.f ? e1 : 0.2f * e1;
    float x0 = expf(e0), x1 = expf(e1);
    float* a = &acc[dl * 13];
    atomicAdd(a + 0, x0 * r0.x); atomicAdd(a + 1, x0 * r0.y);
    atomicAdd(a + 2, x0 * r0.z); atomicAdd(a + 3, x0 * r0.w);
    atomicAdd(a + 4, x0 * r1.x);
    atomicAdd(a + 5, x1 * r1.y); atomicAdd(a + 6, x1 * r1.z);
    atomicAdd(a + 7, x1 * r1.w); atomicAdd(a + 8, x1 * r2.x);
    atomicAdd(a + 9, x1 * r2.y);
    atomicAdd(a + 10, x0); atomicAdd(a + 11, x1);
  }
  __syncthreads();
  if (t < nloc) {
    int n = base_n + t;
    const float4* hs = (const float4*)(h1 + (size_t)n * 16);
    float4 r0 = hs[0], r1 = hs[1], r2 = hs[2];
    float2 adn = adw[t];
    float e0 = r2.z + adn.x; e0 = e0 > 0.f ? e0 : 0.2f * e0;
    float e1 = r2.w + adn.y; e1 = e1 > 0.f ? e1 : 0.2f * e1;
    float x0 = expf(e0), x1 = expf(e1);
    float* a = &acc[t * 13];
    float num[10];
    num[0] = a[0] + x0 * r0.x; num[1] = a[1] + x0 * r0.y;
    num[2] = a[2] + x0 * r0.z; num[3] = a[3] + x0 * r0.w;
    num[4] = a[4] + x0 * r1.x;
    num[5] = a[5] + x1 * r1.y; num[6] = a[6] + x1 * r1.z;
    num[7] = a[7] + x1 * r1.w; num[8] = a[8] + x1 * r2.x;
    num[9] = a[9] + x1 * r2.y;
    float den0 = a[10] + x0, den1 = a[11] + x1;
    float i0 = 1.f / (den0 + 1e-16f), i1 = 1.f / (den1 + 1e-16f);
    float4* gr = (float4*)(g1 + (size_t)n * 12);
    gr[0] = make_float4(num[0] * i0 + b1[0], num[1] * i0 + b1[1],
                        num[2] * i0 + b1[2], num[3] * i0 + b1[3]);
    gr[1] = make_float4(num[4] * i0 + b1[4], num[5] * i1 + b1[5],
                        num[6] * i1 + b1[6], num[7] * i1 + b1[7]);
    gr[2] = make_float4(num[8] * i1 + b1[8], num[9] * i1 + b1[9], 0.f, 0.f);
  }
}

// ---------------- BN statistics over g1 -------------------------------------
__global__ __launch_bounds__(256) void k_bn(const float* __restrict__ g1,
                                            float* __restrict__ bns /*[20]*/) {
  int n = blockIdx.x * blockDim.x + threadIdx.x;
  float v[10];
  if (n < NN) {
    const float4* gr = (const float4*)(g1 + (size_t)n * 12);
    float4 g0 = gr[0], g1v = gr[1], g2 = gr[2];
    v[0] = g0.x; v[1] = g0.y; v[2] = g0.z; v[3] = g0.w; v[4] = g1v.x;
    v[5] = g1v.y; v[6] = g1v.z; v[7] = g1v.w; v[8] = g2.x; v[9] = g2.y;
  } else {
#pragma unroll
    for (int j = 0; j < 10; j++) v[j] = 0.f;
  }
  float sums[20];
#pragma unroll
  for (int j = 0; j < 10; j++) { sums[j] = v[j]; sums[10 + j] = v[j] * v[j]; }
#pragma unroll
  for (int j = 0; j < 20; j++) {
    for (int off = 32; off > 0; off >>= 1) sums[j] += __shfl_down(sums[j], off, 64);
  }
  if ((threadIdx.x & 63) == 0) {
#pragma unroll
    for (int j = 0; j < 20; j++) atomicAdd(&bns[j], sums[j]);
  }
}

// -------- Layer 2 node: BN + ELU + h2 = hn@W2; as2 embedded in row ----------
// h2 row (stride 16): [o0..o9, as2, pad x5]; ad2 separate.
__global__ __launch_bounds__(256) void k_l2_node(
    const float* __restrict__ g1, const float* __restrict__ bns,
    const float* __restrict__ gamma1, const float* __restrict__ beta1,
    const float* __restrict__ W2, const float* __restrict__ a_src2,
    const float* __restrict__ a_dst2, float* __restrict__ h2,
    float* __restrict__ ad2) {
  __shared__ float scale[10], shift[10], W2s[100], a2s[10], a2d[10];
  if (threadIdx.x < 10) {
    int j = threadIdx.x;
    float mu = bns[j] * (1.f / NN);
    float var = bns[10 + j] * (1.f / NN) - mu * mu;
    float rs = rsqrtf(var + 1e-5f);
    scale[j] = rs * gamma1[j];
    shift[j] = beta1[j] - mu * rs * gamma1[j];
    a2s[j] = a_src2[j];
    a2d[j] = a_dst2[j];
  }
  for (int i = threadIdx.x; i < 100; i += blockDim.x) W2s[i] = W2[i];
  __syncthreads();
  int n = blockIdx.x * blockDim.x + threadIdx.x;
  if (n >= NN) return;
  const float4* gr = (const float4*)(g1 + (size_t)n * 12);
  float4 g0 = gr[0], g1v = gr[1], g2 = gr[2];
  float hv[10] = {g0.x, g0.y, g0.z, g0.w, g1v.x, g1v.y, g1v.z, g1v.w, g2.x, g2.y};
#pragma unroll
  for (int j = 0; j < 10; j++) {
    float t = hv[j] * scale[j] + shift[j];
    hv[j] = t > 0.f ? t : expm1f(t);  // ELU
  }
  float o[10];
#pragma unroll
  for (int k = 0; k < 10; k++) o[k] = 0.f;
#pragma unroll
  for (int c = 0; c < 10; c++) {
#pragma unroll
    for (int k = 0; k < 10; k++) o[k] += hv[c] * W2s[c * 10 + k];
  }
  float ss = 0.f, sd = 0.f;
#pragma unroll
  for (int k = 0; k < 10; k++) { ss += o[k] * a2s[k]; sd += o[k] * a2d[k]; }
  float4* hr = (float4*)(h2 + (size_t)n * 16);
  hr[0] = make_float4(o[0], o[1], o[2], o[3]);
  hr[1] = make_float4(o[4], o[5], o[6], o[7]);
  hr[2] = make_float4(o[8], o[9], ss, 0.f);
  ad2[n] = sd;
}

// ------- Layer 2 aggregation: one block per bucket, writes final out --------
__global__ __launch_bounds__(256) void k_l2_aggb(
    const int* __restrict__ bcnt, const unsigned int* __restrict__ pairs,
    const float* __restrict__ h2, const float* __restrict__ ad2,
    const float* __restrict__ b2, float* __restrict__ out) {
  __shared__ float acc[BW * 13];  // per node: num0..9, den (stride 13)
  __shared__ float adw[BW];
  int t = threadIdx.x;
  int b = blockIdx.x;
  int base_n = b << BSH;
  int nloc = NN - base_n < BW ? NN - base_n : BW;
  for (int i = t; i < BW * 13; i += 256) acc[i] = 0.f;
  if (t < BW) adw[t] = (t < nloc) ? ad2[base_n + t] : 0.f;
  __syncthreads();
  int cntb = bcnt[b];
  cntb = cntb > BCAP ? BCAP : cntb;
  const unsigned int* pp = pairs + (size_t)b * BCAP;
  for (int k = t; k < cntb; k += 256) {
    unsigned int e = pp[k];
    int dl = e & (BW - 1);
    int s = e >> BSH;
    const float4* hs = (const float4*)(h2 + (size_t)s * 16);
    float4 r0 = hs[0], r1 = hs[1], r2 = hs[2];
    float ee = r2.z + adw[dl]; ee = ee > 0.f ? ee : 0.2f * ee;
    float xv = expf(ee);
    float* a = &acc[dl * 13];
    atomicAdd(a + 0, xv * r0.x); atomicAdd(a + 1, xv * r0.y);
    atomicAdd(a + 2, xv * r0.z); atomicAdd(a + 3, xv * r0.w);
    atomicAdd(a + 4, xv * r1.x); atomicAdd(a + 5, xv * r1.y);
    atomicAdd(a + 6, xv * r1.z); atomicAdd(a + 7, xv * r1.w);
    atomicAdd(a + 8, xv * r2.x); atomicAdd(a + 9, xv * r2.y);
    atomicAdd(a + 10, xv);
  }
  __syncthreads();
  if (t < nloc) {
    int n = base_n + t;
    const float4* hs = (const float4*)(h2 + (size_t)n * 16);
    float4 r0 = hs[0], r1 = hs[1], r2 = hs[2];
    float ee = r2.z + adw[t]; ee = ee > 0.f ? ee : 0.2f * ee;
    float xv = expf(ee);
    float* a = &acc[t * 13];
    float num[10];
    num[0] = a[0] + xv * r0.x; num[1] = a[1] + xv * r0.y;
    num[2] = a[2] + xv * r0.z; num[3] = a[3] + xv * r0.w;
    num[4] = a[4] + xv * r1.x; num[5] = a[5] + xv * r1.y;
    num[6] = a[6] + xv * r1.z; num[7] = a[7] + xv * r1.w;
    num[8] = a[8] + xv * r2.x; num[9] = a[9] + xv * r2.y;
    float den = a[10] + xv;
    float inv = 1.f / (den + 1e-16f);
    float2* orow = (float2*)(out + (size_t)n * 10);
    orow[0] = make_float2(num[0] * inv + b2[0], num[1] * inv + b2[1]);
    orow[1] = make_float2(num[2] * inv + b2[2], num[3] * inv + b2[3]);
    orow[2] = make_float2(num[4] * inv + b2[4], num[5] * inv + b2[5]);
    orow[3] = make_float2(num[6] * inv + b2[6], num[7] * inv + b2[7]);
    orow[4] = make_float2(num[8] * inv + b2[8], num[9] * inv + b2[9]);
  }
}

extern "C" void kernel_launch(void* const* d_in, const int* in_sizes, int n_in,
                              void* d_out, int out_size, void* d_ws, size_t ws_size,
                              hipStream_t stream) {
  const float* x      = (const float*)d_in[0];
  const float* W1     = (const float*)d_in[1];
  const float* a_src1 = (const float*)d_in[2];
  const float* a_dst1 = (const float*)d_in[3];
  const float* b1     = (const float*)d_in[4];
  const float* gamma1 = (const float*)d_in[5];
  const float* beta1  = (const float*)d_in[6];
  const float* W2     = (const float*)d_in[7];
  const float* a_src2 = (const float*)d_in[8];
  const float* a_dst2 = (const float*)d_in[9];
  const float* b2     = (const float*)d_in[10];
  const int*   ei     = (const int*)d_in[11];
  float* out = (float*)d_out;

  // Workspace layout (4B units). Proven ws_size >= 72MB; this uses ~47.7MB.
  int* bcnt = (int*)d_ws;                               // NBKT (zeroed)
  float* bns = (float*)(bcnt + NBKT);                   // 20 (zeroed)
  unsigned int* pairs = (unsigned int*)d_ws + 1024;     // NBKT*BCAP = 7,206,912
  float* h1 = (float*)(pairs + (size_t)NBKT * BCAP);    // NN*16
  float* ad1 = h1 + (size_t)NN * 16;                    // NN*2
  float* g1 = ad1 + (size_t)NN * 2;                     // NN*12
  float* h2 = g1 + (size_t)NN * 12;                     // NN*16
  float* ad2 = h2 + (size_t)NN * 16;                    // NN

  hipMemsetAsync(d_ws, 0, 4096, stream);  // bcnt + bns

  const int B = 256;
  const int gN = (NN + B - 1) / B;               // 391
  const int gBin = (NE + BIN_CH - 1) / BIN_CH;   // 391

  k_bin<<<gBin, B, 0, stream>>>(ei, bcnt, pairs);
  k_l1_node<<<gN, B, 0, stream>>>(x, W1, a_src1, a_dst1, h1, (float2*)ad1);
  k_l1_aggb<<<NBKT, B, 0, stream>>>(bcnt, pairs, h1, (const float2*)ad1, b1, g1);
  k_bn<<<gN, B, 0, stream>>>(g1, bns);
  k_l2_node<<<gN, B, 0, stream>>>(g1, bns, gamma1, beta1, W2, a_src2, a_dst2,
                                  h2, ad2);
  k_l2_aggb<<<NBKT, B, 0, stream>>>(bcnt, pairs, h2, ad2, b2, out);
}

// Round 5
// 825.605 us; speedup vs baseline: 1.9364x; 1.9364x over previous
//
#include <hip/hip_runtime.h>
#include <math.h>

#define NN 100000
#define NE 6400000
#define INCH 128
#define BSH 7                       // bucket = 128 dst nodes
#define BW (1 << BSH)
#define NBKT ((NN + BW - 1) / BW)   // 782
#define BCAP 9216                   // slots/bucket (mean 8192, +11 sigma)
#define BIN_CH 16384                // edges per bin block

// ------ Binning v2: wave-privatized LDS counters, hierarchical reserve ------
// Entry packing: (src << 7) | (dst & 127)  -- 24 bits used.
__global__ __launch_bounds__(256) void k_bin(const int* __restrict__ ei,
                                             int* __restrict__ bcnt,
                                             unsigned int* __restrict__ pairs) {
  __shared__ int cnt[4][NBKT];    // per-wave private counters / cursors
  __shared__ int wbase[4][NBKT];  // per-wave write base
  int t = threadIdx.x;
  int w = t >> 6;
  for (int i = t; i < 4 * NBKT; i += 256) (&cnt[0][0])[i] = 0;
  __syncthreads();
  int c0 = blockIdx.x * BIN_CH;
  int c1 = c0 + BIN_CH < NE ? c0 + BIN_CH : NE;
  for (int i = c0 + t; i < c1; i += 256) {
    int d = ei[NE + i];
    atomicAdd(&cnt[w][d >> BSH], 1);  // private copy -> low contention
  }
  __syncthreads();
  for (int b = t; b < NBKT; b += 256) {
    int a0 = cnt[0][b], a1 = cnt[1][b], a2 = cnt[2][b], a3 = cnt[3][b];
    int tot = a0 + a1 + a2 + a3;
    int gb = tot > 0 ? atomicAdd(&bcnt[b], tot) : 0;  // 1 global atomic/bucket/block
    wbase[0][b] = gb;
    wbase[1][b] = gb + a0;
    wbase[2][b] = gb + a0 + a1;
    wbase[3][b] = gb + a0 + a1 + a2;
    cnt[0][b] = 0; cnt[1][b] = 0; cnt[2][b] = 0; cnt[3][b] = 0;
  }
  __syncthreads();
  for (int i = c0 + t; i < c1; i += 256) {
    int s = ei[i], d = ei[NE + i];
    int bkt = d >> BSH;
    int pos = wbase[w][bkt] + atomicAdd(&cnt[w][bkt], 1);
    if (pos < BCAP)
      pairs[(size_t)bkt * BCAP + pos] =
          ((unsigned int)s << BSH) | (unsigned int)(d & (BW - 1));
  }
}

// ---------------- Layer 1 node: h1 = x@W1; src logits embedded --------------
// h1 row (stride 16): [h0..h9, -, -, as_x, as_y at .z/.w of r2]; ad1 separate.
__global__ __launch_bounds__(256) void k_l1_node(
    const float* __restrict__ x, const float* __restrict__ W1,
    const float* __restrict__ a_src1, const float* __restrict__ a_dst1,
    float* __restrict__ h1, float2* __restrict__ ad1) {
  __shared__ float Wt[10 * INCH];
  __shared__ float asw[10], adw[10];
  for (int i = threadIdx.x; i < 10 * INCH; i += blockDim.x) {
    int c = i / 10, k = i - c * 10;
    Wt[k * INCH + c] = W1[i];
  }
  if (threadIdx.x < 10) {
    asw[threadIdx.x] = a_src1[threadIdx.x];
    adw[threadIdx.x] = a_dst1[threadIdx.x];
  }
  __syncthreads();
  int n = blockIdx.x * blockDim.x + threadIdx.x;
  if (n >= NN) return;
  const float4* xr = (const float4*)(x + (size_t)n * INCH);
  const float4* Wt4 = (const float4*)Wt;
  float acc[10];
#pragma unroll
  for (int k = 0; k < 10; k++) acc[k] = 0.f;
#pragma unroll 8
  for (int c4 = 0; c4 < INCH / 4; c4++) {
    float4 xv = xr[c4];
#pragma unroll
    for (int k = 0; k < 10; k++) {
      float4 wv = Wt4[k * (INCH / 4) + c4];
      acc[k] += xv.x * wv.x + xv.y * wv.y + xv.z * wv.z + xv.w * wv.w;
    }
  }
  float s0 = 0.f, s1 = 0.f, d0 = 0.f, d1 = 0.f;
#pragma unroll
  for (int j = 0; j < 5; j++) {
    s0 += acc[j] * asw[j];
    s1 += acc[5 + j] * asw[5 + j];
    d0 += acc[j] * adw[j];
    d1 += acc[5 + j] * adw[5 + j];
  }
  float4* hrow = (float4*)(h1 + (size_t)n * 16);
  hrow[0] = make_float4(acc[0], acc[1], acc[2], acc[3]);
  hrow[1] = make_float4(acc[4], acc[5], acc[6], acc[7]);
  hrow[2] = make_float4(acc[8], acc[9], s0, s1);
  ad1[n] = make_float2(d0, d1);
}

// ---- L1 agg: in-LDS counting sort, thread-per-node register accumulation ---
__global__ __launch_bounds__(256) void k_l1_aggs(
    const int* __restrict__ bcnt, const unsigned int* __restrict__ pairs,
    const float* __restrict__ h1, const float2* __restrict__ ad1,
    const float* __restrict__ b1, float* __restrict__ g1) {
  __shared__ int cnt4[4][BW];        // per-wave counts / cursors
  __shared__ int wb[4][BW];          // per-wave scatter base
  __shared__ int offs[BW];           // exclusive segment offset per node
  __shared__ int tot[BW];            // segment length per node
  __shared__ int scanbuf[BW];
  __shared__ unsigned int sorted[BCAP];  // src list grouped by local dst
  __shared__ float partial[BW * 13];
  __shared__ float biasS[10];
  int t = threadIdx.x;
  int w = t >> 6;
  int b = blockIdx.x;
  int base_n = b << BSH;
  int nloc = NN - base_n < BW ? NN - base_n : BW;
  for (int i = t; i < 4 * BW; i += 256) (&cnt4[0][0])[i] = 0;
  if (t < 10) biasS[t] = b1[t];
  __syncthreads();
  int cntb = bcnt[b];
  cntb = cntb > BCAP ? BCAP : cntb;
  const unsigned int* pp = pairs + (size_t)b * BCAP;
  for (int k = t; k < cntb; k += 256)
    atomicAdd(&cnt4[w][pp[k] & (BW - 1)], 1);
  __syncthreads();
  if (t < BW) {
    int tt = cnt4[0][t] + cnt4[1][t] + cnt4[2][t] + cnt4[3][t];
    tot[t] = tt;
    scanbuf[t] = tt;
  }
  __syncthreads();
  for (int step = 1; step < BW; step <<= 1) {  // Hillis-Steele inclusive scan
    int v = 0;
    if (t < BW && t >= step) v = scanbuf[t - step];
    __syncthreads();
    if (t < BW) scanbuf[t] += v;
    __syncthreads();
  }
  if (t < BW) {
    int run = scanbuf[t] - tot[t];
    offs[t] = run;
    wb[0][t] = run; run += cnt4[0][t];
    wb[1][t] = run; run += cnt4[1][t];
    wb[2][t] = run; run += cnt4[2][t];
    wb[3][t] = run;
    cnt4[0][t] = 0; cnt4[1][t] = 0; cnt4[2][t] = 0; cnt4[3][t] = 0;
  }
  __syncthreads();
  for (int k = t; k < cntb; k += 256) {
    unsigned int e = pp[k];
    int dl = e & (BW - 1);
    int pos = wb[w][dl] + atomicAdd(&cnt4[w][dl], 1);
    sorted[pos] = e >> BSH;
  }
  __syncthreads();
  // phase 4: 2 threads per node, serial register accumulation
  int node = t & (BW - 1);
  int part = t >> 7;  // 0 or 1
  bool valid = node < nloc;
  int n = base_n + node;
  float acc[10];
#pragma unroll
  for (int j = 0; j < 10; j++) acc[j] = 0.f;
  float den0 = 0.f, den1 = 0.f;
  float2 adn = valid ? ad1[n] : make_float2(0.f, 0.f);
  int s0i = offs[node], c = valid ? tot[node] : 0;
  for (int k = part; k < c; k += 2) {
    int s = (int)sorted[s0i + k];
    const float4* hs = (const float4*)(h1 + (size_t)s * 16);
    float4 r0 = hs[0], r1 = hs[1], r2 = hs[2];
    float e0 = r2.z + adn.x; e0 = e0 > 0.f ? e0 : 0.2f * e0;
    float e1 = r2.w + adn.y; e1 = e1 > 0.f ? e1 : 0.2f * e1;
    float x0 = expf(e0), x1 = expf(e1);
    acc[0] += x0 * r0.x;  acc[1] += x0 * r0.y;  acc[2] += x0 * r0.z;
    acc[3] += x0 * r0.w;  acc[4] += x0 * r1.x;
    acc[5] += x1 * r1.y;  acc[6] += x1 * r1.z;  acc[7] += x1 * r1.w;
    acc[8] += x1 * r2.x;  acc[9] += x1 * r2.y;
    den0 += x0; den1 += x1;
  }
  if (part == 1) {
    float* pr = &partial[node * 13];
#pragma unroll
    for (int j = 0; j < 10; j++) pr[j] = acc[j];
    pr[10] = den0; pr[11] = den1;
  }
  __syncthreads();
  if (part == 0 && valid) {
    const float* pr = &partial[node * 13];
#pragma unroll
    for (int j = 0; j < 10; j++) acc[j] += pr[j];
    den0 += pr[10]; den1 += pr[11];
    // self-loop (src == dst == n)
    const float4* hs = (const float4*)(h1 + (size_t)n * 16);
    float4 r0 = hs[0], r1 = hs[1], r2 = hs[2];
    float e0 = r2.z + adn.x; e0 = e0 > 0.f ? e0 : 0.2f * e0;
    float e1 = r2.w + adn.y; e1 = e1 > 0.f ? e1 : 0.2f * e1;
    float x0 = expf(e0), x1 = expf(e1);
    acc[0] += x0 * r0.x;  acc[1] += x0 * r0.y;  acc[2] += x0 * r0.z;
    acc[3] += x0 * r0.w;  acc[4] += x0 * r1.x;
    acc[5] += x1 * r1.y;  acc[6] += x1 * r1.z;  acc[7] += x1 * r1.w;
    acc[8] += x1 * r2.x;  acc[9] += x1 * r2.y;
    den0 += x0; den1 += x1;
    float i0 = 1.f / (den0 + 1e-16f), i1 = 1.f / (den1 + 1e-16f);
    float4* gr = (float4*)(g1 + (size_t)n * 12);
    gr[0] = make_float4(acc[0] * i0 + biasS[0], acc[1] * i0 + biasS[1],
                        acc[2] * i0 + biasS[2], acc[3] * i0 + biasS[3]);
    gr[1] = make_float4(acc[4] * i0 + biasS[4], acc[5] * i1 + biasS[5],
                        acc[6] * i1 + biasS[6], acc[7] * i1 + biasS[7]);
    gr[2] = make_float4(acc[8] * i1 + biasS[8], acc[9] * i1 + biasS[9], 0.f, 0.f);
  }
}

// ---------------- BN statistics over g1 -------------------------------------
__global__ __launch_bounds__(256) void k_bn(const float* __restrict__ g1,
                                            float* __restrict__ bns /*[20]*/) {
  int n = blockIdx.x * blockDim.x + threadIdx.x;
  float v[10];
  if (n < NN) {
    const float4* gr = (const float4*)(g1 + (size_t)n * 12);
    float4 g0 = gr[0], g1v = gr[1], g2 = gr[2];
    v[0] = g0.x; v[1] = g0.y; v[2] = g0.z; v[3] = g0.w; v[4] = g1v.x;
    v[5] = g1v.y; v[6] = g1v.z; v[7] = g1v.w; v[8] = g2.x; v[9] = g2.y;
  } else {
#pragma unroll
    for (int j = 0; j < 10; j++) v[j] = 0.f;
  }
  float sums[20];
#pragma unroll
  for (int j = 0; j < 10; j++) { sums[j] = v[j]; sums[10 + j] = v[j] * v[j]; }
#pragma unroll
  for (int j = 0; j < 20; j++) {
    for (int off = 32; off > 0; off >>= 1) sums[j] += __shfl_down(sums[j], off, 64);
  }
  if ((threadIdx.x & 63) == 0) {
#pragma unroll
    for (int j = 0; j < 20; j++) atomicAdd(&bns[j], sums[j]);
  }
}

// -------- Layer 2 node: BN + ELU + h2 = hn@W2; as2 embedded at r2.z ---------
__global__ __launch_bounds__(256) void k_l2_node(
    const float* __restrict__ g1, const float* __restrict__ bns,
    const float* __restrict__ gamma1, const float* __restrict__ beta1,
    const float* __restrict__ W2, const float* __restrict__ a_src2,
    const float* __restrict__ a_dst2, float* __restrict__ h2,
    float* __restrict__ ad2) {
  __shared__ float scale[10], shift[10], W2s[100], a2s[10], a2d[10];
  if (threadIdx.x < 10) {
    int j = threadIdx.x;
    float mu = bns[j] * (1.f / NN);
    float var = bns[10 + j] * (1.f / NN) - mu * mu;
    float rs = rsqrtf(var + 1e-5f);
    scale[j] = rs * gamma1[j];
    shift[j] = beta1[j] - mu * rs * gamma1[j];
    a2s[j] = a_src2[j];
    a2d[j] = a_dst2[j];
  }
  for (int i = threadIdx.x; i < 100; i += blockDim.x) W2s[i] = W2[i];
  __syncthreads();
  int n = blockIdx.x * blockDim.x + threadIdx.x;
  if (n >= NN) return;
  const float4* gr = (const float4*)(g1 + (size_t)n * 12);
  float4 g0 = gr[0], g1v = gr[1], g2 = gr[2];
  float hv[10] = {g0.x, g0.y, g0.z, g0.w, g1v.x, g1v.y, g1v.z, g1v.w, g2.x, g2.y};
#pragma unroll
  for (int j = 0; j < 10; j++) {
    float t = hv[j] * scale[j] + shift[j];
    hv[j] = t > 0.f ? t : expm1f(t);  // ELU
  }
  float o[10];
#pragma unroll
  for (int k = 0; k < 10; k++) o[k] = 0.f;
#pragma unroll
  for (int c = 0; c < 10; c++) {
#pragma unroll
    for (int k = 0; k < 10; k++) o[k] += hv[c] * W2s[c * 10 + k];
  }
  float ss = 0.f, sd = 0.f;
#pragma unroll
  for (int k = 0; k < 10; k++) { ss += o[k] * a2s[k]; sd += o[k] * a2d[k]; }
  float4* hr = (float4*)(h2 + (size_t)n * 16);
  hr[0] = make_float4(o[0], o[1], o[2], o[3]);
  hr[1] = make_float4(o[4], o[5], o[6], o[7]);
  hr[2] = make_float4(o[8], o[9], ss, 0.f);
  ad2[n] = sd;
}

// ---- L2 agg: same structure, 1 head, writes final out ----------------------
__global__ __launch_bounds__(256) void k_l2_aggs(
    const int* __restrict__ bcnt, const unsigned int* __restrict__ pairs,
    const float* __restrict__ h2, const float* __restrict__ ad2,
    const float* __restrict__ b2, float* __restrict__ out) {
  __shared__ int cnt4[4][BW];
  __shared__ int wb[4][BW];
  __shared__ int offs[BW];
  __shared__ int tot[BW];
  __shared__ int scanbuf[BW];
  __shared__ unsigned int sorted[BCAP];
  __shared__ float partial[BW * 13];
  __shared__ float biasS[10];
  int t = threadIdx.x;
  int w = t >> 6;
  int b = blockIdx.x;
  int base_n = b << BSH;
  int nloc = NN - base_n < BW ? NN - base_n : BW;
  for (int i = t; i < 4 * BW; i += 256) (&cnt4[0][0])[i] = 0;
  if (t < 10) biasS[t] = b2[t];
  __syncthreads();
  int cntb = bcnt[b];
  cntb = cntb > BCAP ? BCAP : cntb;
  const unsigned int* pp = pairs + (size_t)b * BCAP;
  for (int k = t; k < cntb; k += 256)
    atomicAdd(&cnt4[w][pp[k] & (BW - 1)], 1);
  __syncthreads();
  if (t < BW) {
    int tt = cnt4[0][t] + cnt4[1][t] + cnt4[2][t] + cnt4[3][t];
    tot[t] = tt;
    scanbuf[t] = tt;
  }
  __syncthreads();
  for (int step = 1; step < BW; step <<= 1) {
    int v = 0;
    if (t < BW && t >= step) v = scanbuf[t - step];
    __syncthreads();
    if (t < BW) scanbuf[t] += v;
    __syncthreads();
  }
  if (t < BW) {
    int run = scanbuf[t] - tot[t];
    offs[t] = run;
    wb[0][t] = run; run += cnt4[0][t];
    wb[1][t] = run; run += cnt4[1][t];
    wb[2][t] = run; run += cnt4[2][t];
    wb[3][t] = run;
    cnt4[0][t] = 0; cnt4[1][t] = 0; cnt4[2][t] = 0; cnt4[3][t] = 0;
  }
  __syncthreads();
  for (int k = t; k < cntb; k += 256) {
    unsigned int e = pp[k];
    int dl = e & (BW - 1);
    int pos = wb[w][dl] + atomicAdd(&cnt4[w][dl], 1);
    sorted[pos] = e >> BSH;
  }
  __syncthreads();
  int node = t & (BW - 1);
  int part = t >> 7;
  bool valid = node < nloc;
  int n = base_n + node;
  float acc[10];
#pragma unroll
  for (int j = 0; j < 10; j++) acc[j] = 0.f;
  float den = 0.f;
  float adn = valid ? ad2[n] : 0.f;
  int s0i = offs[node], c = valid ? tot[node] : 0;
  for (int k = part; k < c; k += 2) {
    int s = (int)sorted[s0i + k];
    const float4* hs = (const float4*)(h2 + (size_t)s * 16);
    float4 r0 = hs[0], r1 = hs[1], r2 = hs[2];
    float ee = r2.z + adn; ee = ee > 0.f ? ee : 0.2f * ee;
    float xv = expf(ee);
    acc[0] += xv * r0.x;  acc[1] += xv * r0.y;  acc[2] += xv * r0.z;
    acc[3] += xv * r0.w;  acc[4] += xv * r1.x;  acc[5] += xv * r1.y;
    acc[6] += xv * r1.z;  acc[7] += xv * r1.w;  acc[8] += xv * r2.x;
    acc[9] += xv * r2.y;
    den += xv;
  }
  if (part == 1) {
    float* pr = &partial[node * 13];
#pragma unroll
    for (int j = 0; j < 10; j++) pr[j] = acc[j];
    pr[10] = den;
  }
  __syncthreads();
  if (part == 0 && valid) {
    const float* pr = &partial[node * 13];
#pragma unroll
    for (int j = 0; j < 10; j++) acc[j] += pr[j];
    den += pr[10];
    const float4* hs = (const float4*)(h2 + (size_t)n * 16);  // self-loop
    float4 r0 = hs[0], r1 = hs[1], r2 = hs[2];
    float ee = r2.z + adn; ee = ee > 0.f ? ee : 0.2f * ee;
    float xv = expf(ee);
    acc[0] += xv * r0.x;  acc[1] += xv * r0.y;  acc[2] += xv * r0.z;
    acc[3] += xv * r0.w;  acc[4] += xv * r1.x;  acc[5] += xv * r1.y;
    acc[6] += xv * r1.z;  acc[7] += xv * r1.w;  acc[8] += xv * r2.x;
    acc[9] += xv * r2.y;
    den += xv;
    float inv = 1.f / (den + 1e-16f);
    float2* orow = (float2*)(out + (size_t)n * 10);
    orow[0] = make_float2(acc[0] * inv + biasS[0], acc[1] * inv + biasS[1]);
    orow[1] = make_float2(acc[2] * inv + biasS[2], acc[3] * inv + biasS[3]);
    orow[2] = make_float2(acc[4] * inv + biasS[4], acc[5] * inv + biasS[5]);
    orow[3] = make_float2(acc[6] * inv + biasS[6], acc[7] * inv + biasS[7]);
    orow[4] = make_float2(acc[8] * inv + biasS[8], acc[9] * inv + biasS[9]);
  }
}

extern "C" void kernel_launch(void* const* d_in, const int* in_sizes, int n_in,
                              void* d_out, int out_size, void* d_ws, size_t ws_size,
                              hipStream_t stream) {
  const float* x      = (const float*)d_in[0];
  const float* W1     = (const float*)d_in[1];
  const float* a_src1 = (const float*)d_in[2];
  const float* a_dst1 = (const float*)d_in[3];
  const float* b1     = (const float*)d_in[4];
  const float* gamma1 = (const float*)d_in[5];
  const float* beta1  = (const float*)d_in[6];
  const float* W2     = (const float*)d_in[7];
  const float* a_src2 = (const float*)d_in[8];
  const float* a_dst2 = (const float*)d_in[9];
  const float* b2     = (const float*)d_in[10];
  const int*   ei     = (const int*)d_in[11];
  float* out = (float*)d_out;

  // Workspace layout (4B units), ~47.7 MB total (72 MB proven available).
  int* bcnt = (int*)d_ws;                               // NBKT (zeroed)
  float* bns = (float*)(bcnt + NBKT);                   // 20 (zeroed)
  unsigned int* pairs = (unsigned int*)d_ws + 1024;     // NBKT*BCAP
  float* h1 = (float*)(pairs + (size_t)NBKT * BCAP);    // NN*16
  float* ad1 = h1 + (size_t)NN * 16;                    // NN*2
  float* g1 = ad1 + (size_t)NN * 2;                     // NN*12
  float* h2 = g1 + (size_t)NN * 12;                     // NN*16
  float* ad2 = h2 + (size_t)NN * 16;                    // NN

  hipMemsetAsync(d_ws, 0, 4096, stream);  // bcnt + bns

  const int B = 256;
  const int gN = (NN + B - 1) / B;               // 391
  const int gBin = (NE + BIN_CH - 1) / BIN_CH;   // 391

  k_bin<<<gBin, B, 0, stream>>>(ei, bcnt, pairs);
  k_l1_node<<<gN, B, 0, stream>>>(x, W1, a_src1, a_dst1, h1, (float2*)ad1);
  k_l1_aggs<<<NBKT, B, 0, stream>>>(bcnt, pairs, h1, (const float2*)ad1, b1, g1);
  k_bn<<<gN, B, 0, stream>>>(g1, bns);
  k_l2_node<<<gN, B, 0, stream>>>(g1, bns, gamma1, beta1, W2, a_src2, a_dst2,
                                  h2, ad2);
  k_l2_aggs<<<NBKT, B, 0, stream>>>(bcnt, pairs, h2, ad2, b2, out);
}

// Round 6
// 508.990 us; speedup vs baseline: 3.1409x; 1.6220x over previous
//
#include <hip/hip_runtime.h>
#include <math.h>

#define NN 100000
#define NE 6400000
#define INCH 128
#define BSH 7                       // bucket = 128 dst nodes
#define BW (1 << BSH)
#define NBKT ((NN + BW - 1) / BW)   // 782
#define BCAP 9216                   // slots/bucket (mean 8192, +11 sigma)
#define BIN_CH 16384                // edges per bin block
#define BNP 800                     // bn_part column stride (>= NBKT)

// ------ Binning: wave-privatized LDS counters, hierarchical reserve ---------
// Entry packing: (src << 7) | (dst & 127)  -- 24 bits used.
__global__ __launch_bounds__(256) void k_bin(const int* __restrict__ ei,
                                             int* __restrict__ bcnt,
                                             unsigned int* __restrict__ pairs) {
  __shared__ int cnt[4][NBKT];    // per-wave private counters / cursors
  __shared__ int wbase[4][NBKT];  // per-wave write base
  int t = threadIdx.x;
  int w = t >> 6;
  for (int i = t; i < 4 * NBKT; i += 256) (&cnt[0][0])[i] = 0;
  __syncthreads();
  int c0 = blockIdx.x * BIN_CH;
  int c1 = c0 + BIN_CH < NE ? c0 + BIN_CH : NE;
  for (int i = c0 + t; i < c1; i += 256) {
    int d = ei[NE + i];
    atomicAdd(&cnt[w][d >> BSH], 1);  // private copy -> low contention
  }
  __syncthreads();
  for (int b = t; b < NBKT; b += 256) {
    int a0 = cnt[0][b], a1 = cnt[1][b], a2 = cnt[2][b], a3 = cnt[3][b];
    int tot = a0 + a1 + a2 + a3;
    int gb = tot > 0 ? atomicAdd(&bcnt[b], tot) : 0;  // 1 global atomic/bucket/block
    wbase[0][b] = gb;
    wbase[1][b] = gb + a0;
    wbase[2][b] = gb + a0 + a1;
    wbase[3][b] = gb + a0 + a1 + a2;
    cnt[0][b] = 0; cnt[1][b] = 0; cnt[2][b] = 0; cnt[3][b] = 0;
  }
  __syncthreads();
  for (int i = c0 + t; i < c1; i += 256) {
    int s = ei[i], d = ei[NE + i];
    int bkt = d >> BSH;
    int pos = wbase[w][bkt] + atomicAdd(&cnt[w][bkt], 1);
    if (pos < BCAP)
      pairs[(size_t)bkt * BCAP + pos] =
          ((unsigned int)s << BSH) | (unsigned int)(d & (BW - 1));
  }
}

// ---------------- Layer 1 node: h1 = x@W1; src logits embedded --------------
// h1 row (stride 16): [h0..h9, -, -, as_x, as_y at r2.z/.w]; ad1 separate.
__global__ __launch_bounds__(256) void k_l1_node(
    const float* __restrict__ x, const float* __restrict__ W1,
    const float* __restrict__ a_src1, const float* __restrict__ a_dst1,
    float* __restrict__ h1, float2* __restrict__ ad1) {
  __shared__ float Wt[10 * INCH];
  __shared__ float asw[10], adw[10];
  for (int i = threadIdx.x; i < 10 * INCH; i += blockDim.x) {
    int c = i / 10, k = i - c * 10;
    Wt[k * INCH + c] = W1[i];
  }
  if (threadIdx.x < 10) {
    asw[threadIdx.x] = a_src1[threadIdx.x];
    adw[threadIdx.x] = a_dst1[threadIdx.x];
  }
  __syncthreads();
  int n = blockIdx.x * blockDim.x + threadIdx.x;
  if (n >= NN) return;
  const float4* xr = (const float4*)(x + (size_t)n * INCH);
  const float4* Wt4 = (const float4*)Wt;
  float acc[10];
#pragma unroll
  for (int k = 0; k < 10; k++) acc[k] = 0.f;
#pragma unroll 8
  for (int c4 = 0; c4 < INCH / 4; c4++) {
    float4 xv = xr[c4];
#pragma unroll
    for (int k = 0; k < 10; k++) {
      float4 wv = Wt4[k * (INCH / 4) + c4];
      acc[k] += xv.x * wv.x + xv.y * wv.y + xv.z * wv.z + xv.w * wv.w;
    }
  }
  float s0 = 0.f, s1 = 0.f, d0 = 0.f, d1 = 0.f;
#pragma unroll
  for (int j = 0; j < 5; j++) {
    s0 += acc[j] * asw[j];
    s1 += acc[5 + j] * asw[5 + j];
    d0 += acc[j] * adw[j];
    d1 += acc[5 + j] * adw[5 + j];
  }
  float4* hrow = (float4*)(h1 + (size_t)n * 16);
  hrow[0] = make_float4(acc[0], acc[1], acc[2], acc[3]);
  hrow[1] = make_float4(acc[4], acc[5], acc[6], acc[7]);
  hrow[2] = make_float4(acc[8], acc[9], s0, s1);
  ad1[n] = make_float2(d0, d1);
}

// ---- L1 agg: in-LDS counting sort, register accumulation, fused BN partials
__global__ __launch_bounds__(256) void k_l1_aggs(
    const int* __restrict__ bcnt, const unsigned int* __restrict__ pairs,
    const float* __restrict__ h1, const float2* __restrict__ ad1,
    const float* __restrict__ b1, float* __restrict__ g1,
    float* __restrict__ bn_part) {
  __shared__ int cnt4[4][BW];        // per-wave counts / cursors
  __shared__ int wb[4][BW];          // per-wave scatter base
  __shared__ int offs[BW];           // exclusive segment offset per node
  __shared__ int tot[BW];            // segment length per node
  __shared__ int scanbuf[BW];
  __shared__ unsigned int sorted[BCAP];  // src list grouped by local dst
  __shared__ float partial[BW * 13];
  __shared__ float biasS[10];
  __shared__ float bn_lds[40];
  int t = threadIdx.x;
  int w = t >> 6;
  int b = blockIdx.x;
  int base_n = b << BSH;
  int nloc = NN - base_n < BW ? NN - base_n : BW;
  for (int i = t; i < 4 * BW; i += 256) (&cnt4[0][0])[i] = 0;
  if (t < 10) biasS[t] = b1[t];
  __syncthreads();
  int cntb = bcnt[b];
  cntb = cntb > BCAP ? BCAP : cntb;
  const unsigned int* pp = pairs + (size_t)b * BCAP;
  for (int k = t; k < cntb; k += 256)
    atomicAdd(&cnt4[w][pp[k] & (BW - 1)], 1);
  __syncthreads();
  if (t < BW) {
    int tt = cnt4[0][t] + cnt4[1][t] + cnt4[2][t] + cnt4[3][t];
    tot[t] = tt;
    scanbuf[t] = tt;
  }
  __syncthreads();
  for (int step = 1; step < BW; step <<= 1) {  // Hillis-Steele inclusive scan
    int v = 0;
    if (t < BW && t >= step) v = scanbuf[t - step];
    __syncthreads();
    if (t < BW) scanbuf[t] += v;
    __syncthreads();
  }
  if (t < BW) {
    int run = scanbuf[t] - tot[t];
    offs[t] = run;
    wb[0][t] = run; run += cnt4[0][t];
    wb[1][t] = run; run += cnt4[1][t];
    wb[2][t] = run; run += cnt4[2][t];
    wb[3][t] = run;
    cnt4[0][t] = 0; cnt4[1][t] = 0; cnt4[2][t] = 0; cnt4[3][t] = 0;
  }
  __syncthreads();
  for (int k = t; k < cntb; k += 256) {
    unsigned int e = pp[k];
    int dl = e & (BW - 1);
    int pos = wb[w][dl] + atomicAdd(&cnt4[w][dl], 1);
    sorted[pos] = e >> BSH;
  }
  __syncthreads();
  // phase 4: 2 threads per node, serial register accumulation
  int node = t & (BW - 1);
  int part = t >> 7;  // 0 or 1 (wave-uniform)
  bool valid = node < nloc;
  int n = base_n + node;
  float acc[10];
#pragma unroll
  for (int j = 0; j < 10; j++) acc[j] = 0.f;
  float den0 = 0.f, den1 = 0.f;
  float2 adn = valid ? ad1[n] : make_float2(0.f, 0.f);
  int s0i = offs[node], c = valid ? tot[node] : 0;
  for (int k = part; k < c; k += 2) {
    int s = (int)sorted[s0i + k];
    const float4* hs = (const float4*)(h1 + (size_t)s * 16);
    float4 r0 = hs[0], r1 = hs[1], r2 = hs[2];
    float e0 = r2.z + adn.x; e0 = e0 > 0.f ? e0 : 0.2f * e0;
    float e1 = r2.w + adn.y; e1 = e1 > 0.f ? e1 : 0.2f * e1;
    float x0 = expf(e0), x1 = expf(e1);
    acc[0] += x0 * r0.x;  acc[1] += x0 * r0.y;  acc[2] += x0 * r0.z;
    acc[3] += x0 * r0.w;  acc[4] += x0 * r1.x;
    acc[5] += x1 * r1.y;  acc[6] += x1 * r1.z;  acc[7] += x1 * r1.w;
    acc[8] += x1 * r2.x;  acc[9] += x1 * r2.y;
    den0 += x0; den1 += x1;
  }
  if (part == 1) {
    float* pr = &partial[node * 13];
#pragma unroll
    for (int j = 0; j < 10; j++) pr[j] = acc[j];
    pr[10] = den0; pr[11] = den1;
  }
  __syncthreads();
  if (part == 0) {  // waves 0,1
    float v[10];
    if (valid) {
      const float* pr = &partial[node * 13];
#pragma unroll
      for (int j = 0; j < 10; j++) acc[j] += pr[j];
      den0 += pr[10]; den1 += pr[11];
      // self-loop (src == dst == n)
      const float4* hs = (const float4*)(h1 + (size_t)n * 16);
      float4 r0 = hs[0], r1 = hs[1], r2 = hs[2];
      float e0 = r2.z + adn.x; e0 = e0 > 0.f ? e0 : 0.2f * e0;
      float e1 = r2.w + adn.y; e1 = e1 > 0.f ? e1 : 0.2f * e1;
      float x0 = expf(e0), x1 = expf(e1);
      acc[0] += x0 * r0.x;  acc[1] += x0 * r0.y;  acc[2] += x0 * r0.z;
      acc[3] += x0 * r0.w;  acc[4] += x0 * r1.x;
      acc[5] += x1 * r1.y;  acc[6] += x1 * r1.z;  acc[7] += x1 * r1.w;
      acc[8] += x1 * r2.x;  acc[9] += x1 * r2.y;
      den0 += x0; den1 += x1;
      float i0 = 1.f / (den0 + 1e-16f), i1 = 1.f / (den1 + 1e-16f);
#pragma unroll
      for (int j = 0; j < 5; j++) v[j] = acc[j] * i0 + biasS[j];
#pragma unroll
      for (int j = 5; j < 10; j++) v[j] = acc[j] * i1 + biasS[j];
      float4* gr = (float4*)(g1 + (size_t)n * 12);
      gr[0] = make_float4(v[0], v[1], v[2], v[3]);
      gr[1] = make_float4(v[4], v[5], v[6], v[7]);
      gr[2] = make_float4(v[8], v[9], 0.f, 0.f);
    } else {
#pragma unroll
      for (int j = 0; j < 10; j++) v[j] = 0.f;
    }
    // BN partials: reduce 20 quantities across each of waves 0,1
    float s[20];
#pragma unroll
    for (int j = 0; j < 10; j++) { s[j] = v[j]; s[10 + j] = v[j] * v[j]; }
#pragma unroll
    for (int j = 0; j < 20; j++) {
      for (int off = 32; off > 0; off >>= 1) s[j] += __shfl_down(s[j], off, 64);
    }
    if ((t & 63) == 0) {
#pragma unroll
      for (int j = 0; j < 20; j++) bn_lds[w * 20 + j] = s[j];
    }
  }
  __syncthreads();
  if (t == 0) {
#pragma unroll
    for (int j = 0; j < 20; j++)
      bn_part[j * BNP + b] = bn_lds[j] + bn_lds[20 + j];  // unique slot, no atomic
  }
}

// ---- BN final reduce: one block per channel-stat, no contended atomics -----
__global__ __launch_bounds__(64) void k_bnred(const float* __restrict__ bn_part,
                                              float* __restrict__ bns) {
  int j = blockIdx.x;  // 0..19
  int lane = threadIdx.x;
  float s = 0.f;
  for (int b = lane; b < NBKT; b += 64) s += bn_part[j * BNP + b];
#pragma unroll
  for (int off = 32; off > 0; off >>= 1) s += __shfl_down(s, off, 64);
  if (lane == 0) bns[j] = s;
}

// -------- Layer 2 node: BN + ELU + h2 = hn@W2; as2 embedded at r2.z ---------
__global__ __launch_bounds__(256) void k_l2_node(
    const float* __restrict__ g1, const float* __restrict__ bns,
    const float* __restrict__ gamma1, const float* __restrict__ beta1,
    const float* __restrict__ W2, const float* __restrict__ a_src2,
    const float* __restrict__ a_dst2, float* __restrict__ h2,
    float* __restrict__ ad2) {
  __shared__ float scale[10], shift[10], W2s[100], a2s[10], a2d[10];
  if (threadIdx.x < 10) {
    int j = threadIdx.x;
    float mu = bns[j] * (1.f / NN);
    float var = bns[10 + j] * (1.f / NN) - mu * mu;
    float rs = rsqrtf(var + 1e-5f);
    scale[j] = rs * gamma1[j];
    shift[j] = beta1[j] - mu * rs * gamma1[j];
    a2s[j] = a_src2[j];
    a2d[j] = a_dst2[j];
  }
  for (int i = threadIdx.x; i < 100; i += blockDim.x) W2s[i] = W2[i];
  __syncthreads();
  int n = blockIdx.x * blockDim.x + threadIdx.x;
  if (n >= NN) return;
  const float4* gr = (const float4*)(g1 + (size_t)n * 12);
  float4 g0 = gr[0], g1v = gr[1], g2 = gr[2];
  float hv[10] = {g0.x, g0.y, g0.z, g0.w, g1v.x, g1v.y, g1v.z, g1v.w, g2.x, g2.y};
#pragma unroll
  for (int j = 0; j < 10; j++) {
    float t = hv[j] * scale[j] + shift[j];
    hv[j] = t > 0.f ? t : expm1f(t);  // ELU
  }
  float o[10];
#pragma unroll
  for (int k = 0; k < 10; k++) o[k] = 0.f;
#pragma unroll
  for (int c = 0; c < 10; c++) {
#pragma unroll
    for (int k = 0; k < 10; k++) o[k] += hv[c] * W2s[c * 10 + k];
  }
  float ss = 0.f, sd = 0.f;
#pragma unroll
  for (int k = 0; k < 10; k++) { ss += o[k] * a2s[k]; sd += o[k] * a2d[k]; }
  float4* hr = (float4*)(h2 + (size_t)n * 16);
  hr[0] = make_float4(o[0], o[1], o[2], o[3]);
  hr[1] = make_float4(o[4], o[5], o[6], o[7]);
  hr[2] = make_float4(o[8], o[9], ss, 0.f);
  ad2[n] = sd;
}

// ---- L2 agg: same structure, 1 head, writes final out ----------------------
__global__ __launch_bounds__(256) void k_l2_aggs(
    const int* __restrict__ bcnt, const unsigned int* __restrict__ pairs,
    const float* __restrict__ h2, const float* __restrict__ ad2,
    const float* __restrict__ b2, float* __restrict__ out) {
  __shared__ int cnt4[4][BW];
  __shared__ int wb[4][BW];
  __shared__ int offs[BW];
  __shared__ int tot[BW];
  __shared__ int scanbuf[BW];
  __shared__ unsigned int sorted[BCAP];
  __shared__ float partial[BW * 13];
  __shared__ float biasS[10];
  int t = threadIdx.x;
  int w = t >> 6;
  int b = blockIdx.x;
  int base_n = b << BSH;
  int nloc = NN - base_n < BW ? NN - base_n : BW;
  for (int i = t; i < 4 * BW; i += 256) (&cnt4[0][0])[i] = 0;
  if (t < 10) biasS[t] = b2[t];
  __syncthreads();
  int cntb = bcnt[b];
  cntb = cntb > BCAP ? BCAP : cntb;
  const unsigned int* pp = pairs + (size_t)b * BCAP;
  for (int k = t; k < cntb; k += 256)
    atomicAdd(&cnt4[w][pp[k] & (BW - 1)], 1);
  __syncthreads();
  if (t < BW) {
    int tt = cnt4[0][t] + cnt4[1][t] + cnt4[2][t] + cnt4[3][t];
    tot[t] = tt;
    scanbuf[t] = tt;
  }
  __syncthreads();
  for (int step = 1; step < BW; step <<= 1) {
    int v = 0;
    if (t < BW && t >= step) v = scanbuf[t - step];
    __syncthreads();
    if (t < BW) scanbuf[t] += v;
    __syncthreads();
  }
  if (t < BW) {
    int run = scanbuf[t] - tot[t];
    offs[t] = run;
    wb[0][t] = run; run += cnt4[0][t];
    wb[1][t] = run; run += cnt4[1][t];
    wb[2][t] = run; run += cnt4[2][t];
    wb[3][t] = run;
    cnt4[0][t] = 0; cnt4[1][t] = 0; cnt4[2][t] = 0; cnt4[3][t] = 0;
  }
  __syncthreads();
  for (int k = t; k < cntb; k += 256) {
    unsigned int e = pp[k];
    int dl = e & (BW - 1);
    int pos = wb[w][dl] + atomicAdd(&cnt4[w][dl], 1);
    sorted[pos] = e >> BSH;
  }
  __syncthreads();
  int node = t & (BW - 1);
  int part = t >> 7;
  bool valid = node < nloc;
  int n = base_n + node;
  float acc[10];
#pragma unroll
  for (int j = 0; j < 10; j++) acc[j] = 0.f;
  float den = 0.f;
  float adn = valid ? ad2[n] : 0.f;
  int s0i = offs[node], c = valid ? tot[node] : 0;
  for (int k = part; k < c; k += 2) {
    int s = (int)sorted[s0i + k];
    const float4* hs = (const float4*)(h2 + (size_t)s * 16);
    float4 r0 = hs[0], r1 = hs[1], r2 = hs[2];
    float ee = r2.z + adn; ee = ee > 0.f ? ee : 0.2f * ee;
    float xv = expf(ee);
    acc[0] += xv * r0.x;  acc[1] += xv * r0.y;  acc[2] += xv * r0.z;
    acc[3] += xv * r0.w;  acc[4] += xv * r1.x;  acc[5] += xv * r1.y;
    acc[6] += xv * r1.z;  acc[7] += xv * r1.w;  acc[8] += xv * r2.x;
    acc[9] += xv * r2.y;
    den += xv;
  }
  if (part == 1) {
    float* pr = &partial[node * 13];
#pragma unroll
    for (int j = 0; j < 10; j++) pr[j] = acc[j];
    pr[10] = den;
  }
  __syncthreads();
  if (part == 0 && valid) {
    const float* pr = &partial[node * 13];
#pragma unroll
    for (int j = 0; j < 10; j++) acc[j] += pr[j];
    den += pr[10];
    const float4* hs = (const float4*)(h2 + (size_t)n * 16);  // self-loop
    float4 r0 = hs[0], r1 = hs[1], r2 = hs[2];
    float ee = r2.z + adn; ee = ee > 0.f ? ee : 0.2f * ee;
    float xv = expf(ee);
    acc[0] += xv * r0.x;  acc[1] += xv * r0.y;  acc[2] += xv * r0.z;
    acc[3] += xv * r0.w;  acc[4] += xv * r1.x;  acc[5] += xv * r1.y;
    acc[6] += xv * r1.z;  acc[7] += xv * r1.w;  acc[8] += xv * r2.x;
    acc[9] += xv * r2.y;
    den += xv;
    float inv = 1.f / (den + 1e-16f);
    float2* orow = (float2*)(out + (size_t)n * 10);
    orow[0] = make_float2(acc[0] * inv + biasS[0], acc[1] * inv + biasS[1]);
    orow[1] = make_float2(acc[2] * inv + biasS[2], acc[3] * inv + biasS[3]);
    orow[2] = make_float2(acc[4] * inv + biasS[4], acc[5] * inv + biasS[5]);
    orow[3] = make_float2(acc[6] * inv + biasS[6], acc[7] * inv + biasS[7]);
    orow[4] = make_float2(acc[8] * inv + biasS[8], acc[9] * inv + biasS[9]);
  }
}

extern "C" void kernel_launch(void* const* d_in, const int* in_sizes, int n_in,
                              void* d_out, int out_size, void* d_ws, size_t ws_size,
                              hipStream_t stream) {
  const float* x      = (const float*)d_in[0];
  const float* W1     = (const float*)d_in[1];
  const float* a_src1 = (const float*)d_in[2];
  const float* a_dst1 = (const float*)d_in[3];
  const float* b1     = (const float*)d_in[4];
  const float* gamma1 = (const float*)d_in[5];
  const float* beta1  = (const float*)d_in[6];
  const float* W2     = (const float*)d_in[7];
  const float* a_src2 = (const float*)d_in[8];
  const float* a_dst2 = (const float*)d_in[9];
  const float* b2     = (const float*)d_in[10];
  const int*   ei     = (const int*)d_in[11];
  float* out = (float*)d_out;

  // Workspace layout (4B units), ~47.8 MB total (72 MB proven available).
  int* bcnt = (int*)d_ws;                               // NBKT (zeroed)
  unsigned int* pairs = (unsigned int*)d_ws + 1024;     // NBKT*BCAP
  float* h1 = (float*)(pairs + (size_t)NBKT * BCAP);    // NN*16
  float* ad1 = h1 + (size_t)NN * 16;                    // NN*2
  float* g1 = ad1 + (size_t)NN * 2;                     // NN*12
  float* h2 = g1 + (size_t)NN * 12;                     // NN*16
  float* ad2 = h2 + (size_t)NN * 16;                    // NN
  float* bn_part = ad2 + NN;                            // 20*BNP (fully written)
  float* bns = bn_part + 20 * BNP;                      // 20 (written by k_bnred)

  hipMemsetAsync(d_ws, 0, 4096, stream);  // bcnt

  const int B = 256;
  const int gN = (NN + B - 1) / B;               // 391
  const int gBin = (NE + BIN_CH - 1) / BIN_CH;   // 391

  k_bin<<<gBin, B, 0, stream>>>(ei, bcnt, pairs);
  k_l1_node<<<gN, B, 0, stream>>>(x, W1, a_src1, a_dst1, h1, (float2*)ad1);
  k_l1_aggs<<<NBKT, B, 0, stream>>>(bcnt, pairs, h1, (const float2*)ad1, b1, g1,
                                    bn_part);
  k_bnred<<<20, 64, 0, stream>>>(bn_part, bns);
  k_l2_node<<<gN, B, 0, stream>>>(g1, bns, gamma1, beta1, W2, a_src2, a_dst2,
                                  h2, ad2);
  k_l2_aggs<<<NBKT, B, 0, stream>>>(bcnt, pairs, h2, ad2, b2, out);
}

// Round 7
// 467.512 us; speedup vs baseline: 3.4195x; 1.0887x over previous
//
#include <hip/hip_runtime.h>
#include <math.h>

#define NN 100000
#define NE 6400000
#define INCH 128
#define BSH 7                       // bucket = 128 dst nodes
#define BW (1 << BSH)
#define NBKT ((NN + BW - 1) / BW)   // 782
#define BCAP 9216                   // slots/bucket (mean 8192, +11 sigma)
#define BIN_CH 8192                 // edges per bin block
#define BNP 800                     // bn_part column stride (>= NBKT)

// ------ Binning v3: LDS-staged counting sort per chunk, coalesced flush -----
// Entry packing: (src << 7) | (dst & 127)  -- 24 bits used.
__global__ __launch_bounds__(256) void k_bin(const int* __restrict__ ei,
                                             int* __restrict__ bcnt,
                                             unsigned int* __restrict__ pairs) {
  __shared__ int cnt4[4][NBKT];        // per-wave private counts
  __shared__ int wb4[4][NBKT];         // per-wave LDS staging cursors
  __shared__ int offs[NBKT + 1];       // staging exclusive offsets (+sentinel)
  __shared__ int gbase[NBKT];          // reserved global base per bucket
  __shared__ int scanp[256];
  __shared__ unsigned int stage[BIN_CH];
  int t = threadIdx.x;
  int w = t >> 6;
  for (int i = t; i < 4 * NBKT; i += 256) (&cnt4[0][0])[i] = 0;
  __syncthreads();
  int c0 = blockIdx.x * BIN_CH;
  int c1 = c0 + BIN_CH < NE ? c0 + BIN_CH : NE;
  // pass A: per-wave histogram of dst buckets
  for (int i = c0 + t; i < c1; i += 256)
    atomicAdd(&cnt4[w][ei[NE + i] >> BSH], 1);
  __syncthreads();
  // block-level exclusive scan over 782 bucket totals (4 buckets/thread)
  int myb0 = t * 4;
  int tots[4];
  int asum = 0;
#pragma unroll
  for (int j = 0; j < 4; j++) {
    int b = myb0 + j;
    int tt = (b < NBKT) ? cnt4[0][b] + cnt4[1][b] + cnt4[2][b] + cnt4[3][b] : 0;
    tots[j] = tt;
    asum += tt;
  }
  scanp[t] = asum;
  __syncthreads();
  for (int off = 1; off < 256; off <<= 1) {
    int v = (t >= off) ? scanp[t - off] : 0;
    __syncthreads();
    scanp[t] += v;
    __syncthreads();
  }
  int run = (t == 0) ? 0 : scanp[t - 1];
#pragma unroll
  for (int j = 0; j < 4; j++) {
    int b = myb0 + j;
    if (b < NBKT) {
      int tt = tots[j];
      offs[b] = run;
      gbase[b] = tt > 0 ? atomicAdd(&bcnt[b], tt) : 0;  // 1 global atomic/bucket
      wb4[0][b] = run;
      wb4[1][b] = run + cnt4[0][b];
      wb4[2][b] = wb4[1][b] + cnt4[1][b];
      wb4[3][b] = wb4[2][b] + cnt4[2][b];
      run += tt;
    }
  }
  if (t == 255) offs[NBKT] = scanp[255];  // sentinel = chunk size
  __syncthreads();
  // pass B: scatter packed entries into LDS staging (bucket-grouped)
  for (int i = c0 + t; i < c1; i += 256) {
    int s = ei[i], d = ei[NE + i];
    int bkt = d >> BSH;
    int pos = atomicAdd(&wb4[w][bkt], 1);
    stage[pos] = ((unsigned int)s << BSH) | (unsigned int)(d & (BW - 1));
  }
  __syncthreads();
  // flush: consecutive threads -> consecutive global addrs within bucket runs
  int total = offs[NBKT];
  for (int i = t; i < total; i += 256) {
    unsigned int e = stage[i];
    int lo = 0, hi = NBKT - 1;  // largest b with offs[b] <= i
    while (lo < hi) {
      int mid = (lo + hi + 1) >> 1;
      if (offs[mid] <= i) lo = mid; else hi = mid - 1;
    }
    int gp = gbase[lo] + (i - offs[lo]);
    if (gp < BCAP) pairs[(size_t)lo * BCAP + gp] = e;
  }
}

// ---------------- Layer 1 node: h1 = x@W1; src logits embedded --------------
// h1 row (stride 16): [h0..h9, -, -, as_x, as_y at r2.z/.w]; ad1 separate.
__global__ __launch_bounds__(256) void k_l1_node(
    const float* __restrict__ x, const float* __restrict__ W1,
    const float* __restrict__ a_src1, const float* __restrict__ a_dst1,
    float* __restrict__ h1, float2* __restrict__ ad1) {
  __shared__ float Wt[10 * INCH];
  __shared__ float asw[10], adw[10];
  for (int i = threadIdx.x; i < 10 * INCH; i += blockDim.x) {
    int c = i / 10, k = i - c * 10;
    Wt[k * INCH + c] = W1[i];
  }
  if (threadIdx.x < 10) {
    asw[threadIdx.x] = a_src1[threadIdx.x];
    adw[threadIdx.x] = a_dst1[threadIdx.x];
  }
  __syncthreads();
  int n = blockIdx.x * blockDim.x + threadIdx.x;
  if (n >= NN) return;
  const float4* xr = (const float4*)(x + (size_t)n * INCH);
  const float4* Wt4 = (const float4*)Wt;
  float acc[10];
#pragma unroll
  for (int k = 0; k < 10; k++) acc[k] = 0.f;
#pragma unroll 8
  for (int c4 = 0; c4 < INCH / 4; c4++) {
    float4 xv = xr[c4];
#pragma unroll
    for (int k = 0; k < 10; k++) {
      float4 wv = Wt4[k * (INCH / 4) + c4];
      acc[k] += xv.x * wv.x + xv.y * wv.y + xv.z * wv.z + xv.w * wv.w;
    }
  }
  float s0 = 0.f, s1 = 0.f, d0 = 0.f, d1 = 0.f;
#pragma unroll
  for (int j = 0; j < 5; j++) {
    s0 += acc[j] * asw[j];
    s1 += acc[5 + j] * asw[5 + j];
    d0 += acc[j] * adw[j];
    d1 += acc[5 + j] * adw[5 + j];
  }
  float4* hrow = (float4*)(h1 + (size_t)n * 16);
  hrow[0] = make_float4(acc[0], acc[1], acc[2], acc[3]);
  hrow[1] = make_float4(acc[4], acc[5], acc[6], acc[7]);
  hrow[2] = make_float4(acc[8], acc[9], s0, s1);
  ad1[n] = make_float2(d0, d1);
}

// ---- L1 agg: LDS counting sort, 4 threads/node reg accumulation, BN fused --
__global__ __launch_bounds__(512, 4) void k_l1_aggs(
    const int* __restrict__ bcnt, const unsigned int* __restrict__ pairs,
    const float* __restrict__ h1, const float2* __restrict__ ad1,
    const float* __restrict__ b1, float* __restrict__ g1,
    float* __restrict__ bn_part) {
  __shared__ int cnt8[8][BW];        // per-wave counts / cursors
  __shared__ int wb[8][BW];          // per-wave scatter base
  __shared__ int offs[BW];
  __shared__ int tot[BW];
  __shared__ int scanbuf[BW];
  __shared__ unsigned int sorted[BCAP];
  __shared__ float partial[3 * BW * 13];  // parts 1..3
  __shared__ float biasS[10];
  __shared__ float bn_lds[40];
  int t = threadIdx.x;
  int w = t >> 6;
  int b = blockIdx.x;
  int base_n = b << BSH;
  int nloc = NN - base_n < BW ? NN - base_n : BW;
  for (int i = t; i < 8 * BW; i += 512) (&cnt8[0][0])[i] = 0;
  if (t < 10) biasS[t] = b1[t];
  __syncthreads();
  int cntb = bcnt[b];
  cntb = cntb > BCAP ? BCAP : cntb;
  const unsigned int* pp = pairs + (size_t)b * BCAP;
  for (int k = t; k < cntb; k += 512)
    atomicAdd(&cnt8[w][pp[k] & (BW - 1)], 1);
  __syncthreads();
  if (t < BW) {
    int tt = 0;
#pragma unroll
    for (int j = 0; j < 8; j++) tt += cnt8[j][t];
    tot[t] = tt;
    scanbuf[t] = tt;
  }
  __syncthreads();
  for (int step = 1; step < BW; step <<= 1) {  // Hillis-Steele inclusive scan
    int v = 0;
    if (t < BW && t >= step) v = scanbuf[t - step];
    __syncthreads();
    if (t < BW) scanbuf[t] += v;
    __syncthreads();
  }
  if (t < BW) {
    int run = scanbuf[t] - tot[t];
    offs[t] = run;
#pragma unroll
    for (int j = 0; j < 8; j++) { wb[j][t] = run; run += cnt8[j][t]; cnt8[j][t] = 0; }
  }
  __syncthreads();
  for (int k = t; k < cntb; k += 512) {
    unsigned int e = pp[k];
    int dl = e & (BW - 1);
    int pos = wb[w][dl] + atomicAdd(&cnt8[w][dl], 1);
    sorted[pos] = e >> BSH;
  }
  __syncthreads();
  // phase 4: 4 threads per node, serial register accumulation
  int node = t & (BW - 1);
  int part = t >> 7;  // 0..3 (wave-uniform pairs)
  bool valid = node < nloc;
  int n = base_n + node;
  float acc[10];
#pragma unroll
  for (int j = 0; j < 10; j++) acc[j] = 0.f;
  float den0 = 0.f, den1 = 0.f;
  float2 adn = valid ? ad1[n] : make_float2(0.f, 0.f);
  int s0i = offs[node], c = valid ? tot[node] : 0;
  for (int k = part; k < c; k += 4) {
    int s = (int)sorted[s0i + k];
    const float4* hs = (const float4*)(h1 + (size_t)s * 16);
    float4 r0 = hs[0], r1 = hs[1], r2 = hs[2];
    float e0 = r2.z + adn.x; e0 = e0 > 0.f ? e0 : 0.2f * e0;
    float e1 = r2.w + adn.y; e1 = e1 > 0.f ? e1 : 0.2f * e1;
    float x0 = expf(e0), x1 = expf(e1);
    acc[0] += x0 * r0.x;  acc[1] += x0 * r0.y;  acc[2] += x0 * r0.z;
    acc[3] += x0 * r0.w;  acc[4] += x0 * r1.x;
    acc[5] += x1 * r1.y;  acc[6] += x1 * r1.z;  acc[7] += x1 * r1.w;
    acc[8] += x1 * r2.x;  acc[9] += x1 * r2.y;
    den0 += x0; den1 += x1;
  }
  if (part > 0) {
    float* pr = &partial[((part - 1) * BW + node) * 13];
#pragma unroll
    for (int j = 0; j < 10; j++) pr[j] = acc[j];
    pr[10] = den0; pr[11] = den1;
  }
  __syncthreads();
  if (part == 0) {  // waves 0,1
    float v[10];
    if (valid) {
#pragma unroll
      for (int p = 0; p < 3; p++) {
        const float* pr = &partial[(p * BW + node) * 13];
#pragma unroll
        for (int j = 0; j < 10; j++) acc[j] += pr[j];
        den0 += pr[10]; den1 += pr[11];
      }
      // self-loop (src == dst == n)
      const float4* hs = (const float4*)(h1 + (size_t)n * 16);
      float4 r0 = hs[0], r1 = hs[1], r2 = hs[2];
      float e0 = r2.z + adn.x; e0 = e0 > 0.f ? e0 : 0.2f * e0;
      float e1 = r2.w + adn.y; e1 = e1 > 0.f ? e1 : 0.2f * e1;
      float x0 = expf(e0), x1 = expf(e1);
      acc[0] += x0 * r0.x;  acc[1] += x0 * r0.y;  acc[2] += x0 * r0.z;
      acc[3] += x0 * r0.w;  acc[4] += x0 * r1.x;
      acc[5] += x1 * r1.y;  acc[6] += x1 * r1.z;  acc[7] += x1 * r1.w;
      acc[8] += x1 * r2.x;  acc[9] += x1 * r2.y;
      den0 += x0; den1 += x1;
      float i0 = 1.f / (den0 + 1e-16f), i1 = 1.f / (den1 + 1e-16f);
#pragma unroll
      for (int j = 0; j < 5; j++) v[j] = acc[j] * i0 + biasS[j];
#pragma unroll
      for (int j = 5; j < 10; j++) v[j] = acc[j] * i1 + biasS[j];
      float4* gr = (float4*)(g1 + (size_t)n * 12);
      gr[0] = make_float4(v[0], v[1], v[2], v[3]);
      gr[1] = make_float4(v[4], v[5], v[6], v[7]);
      gr[2] = make_float4(v[8], v[9], 0.f, 0.f);
    } else {
#pragma unroll
      for (int j = 0; j < 10; j++) v[j] = 0.f;
    }
    // BN partials: reduce 20 quantities across each of waves 0,1
    float s[20];
#pragma unroll
    for (int j = 0; j < 10; j++) { s[j] = v[j]; s[10 + j] = v[j] * v[j]; }
#pragma unroll
    for (int j = 0; j < 20; j++) {
      for (int off = 32; off > 0; off >>= 1) s[j] += __shfl_down(s[j], off, 64);
    }
    if ((t & 63) == 0) {
#pragma unroll
      for (int j = 0; j < 20; j++) bn_lds[w * 20 + j] = s[j];
    }
  }
  __syncthreads();
  if (t == 0) {
#pragma unroll
    for (int j = 0; j < 20; j++)
      bn_part[j * BNP + b] = bn_lds[j] + bn_lds[20 + j];  // unique slot, no atomic
  }
}

// ---- BN final reduce: one block per channel-stat, no contended atomics -----
__global__ __launch_bounds__(64) void k_bnred(const float* __restrict__ bn_part,
                                              float* __restrict__ bns) {
  int j = blockIdx.x;  // 0..19
  int lane = threadIdx.x;
  float s = 0.f;
  for (int b = lane; b < NBKT; b += 64) s += bn_part[j * BNP + b];
#pragma unroll
  for (int off = 32; off > 0; off >>= 1) s += __shfl_down(s, off, 64);
  if (lane == 0) bns[j] = s;
}

// -------- Layer 2 node: BN + ELU + h2 = hn@W2; as2 embedded at r2.z ---------
__global__ __launch_bounds__(256) void k_l2_node(
    const float* __restrict__ g1, const float* __restrict__ bns,
    const float* __restrict__ gamma1, const float* __restrict__ beta1,
    const float* __restrict__ W2, const float* __restrict__ a_src2,
    const float* __restrict__ a_dst2, float* __restrict__ h2,
    float* __restrict__ ad2) {
  __shared__ float scale[10], shift[10], W2s[100], a2s[10], a2d[10];
  if (threadIdx.x < 10) {
    int j = threadIdx.x;
    float mu = bns[j] * (1.f / NN);
    float var = bns[10 + j] * (1.f / NN) - mu * mu;
    float rs = rsqrtf(var + 1e-5f);
    scale[j] = rs * gamma1[j];
    shift[j] = beta1[j] - mu * rs * gamma1[j];
    a2s[j] = a_src2[j];
    a2d[j] = a_dst2[j];
  }
  for (int i = threadIdx.x; i < 100; i += blockDim.x) W2s[i] = W2[i];
  __syncthreads();
  int n = blockIdx.x * blockDim.x + threadIdx.x;
  if (n >= NN) return;
  const float4* gr = (const float4*)(g1 + (size_t)n * 12);
  float4 g0 = gr[0], g1v = gr[1], g2 = gr[2];
  float hv[10] = {g0.x, g0.y, g0.z, g0.w, g1v.x, g1v.y, g1v.z, g1v.w, g2.x, g2.y};
#pragma unroll
  for (int j = 0; j < 10; j++) {
    float t = hv[j] * scale[j] + shift[j];
    hv[j] = t > 0.f ? t : expm1f(t);  // ELU
  }
  float o[10];
#pragma unroll
  for (int k = 0; k < 10; k++) o[k] = 0.f;
#pragma unroll
  for (int c = 0; c < 10; c++) {
#pragma unroll
    for (int k = 0; k < 10; k++) o[k] += hv[c] * W2s[c * 10 + k];
  }
  float ss = 0.f, sd = 0.f;
#pragma unroll
  for (int k = 0; k < 10; k++) { ss += o[k] * a2s[k]; sd += o[k] * a2d[k]; }
  float4* hr = (float4*)(h2 + (size_t)n * 16);
  hr[0] = make_float4(o[0], o[1], o[2], o[3]);
  hr[1] = make_float4(o[4], o[5], o[6], o[7]);
  hr[2] = make_float4(o[8], o[9], ss, 0.f);
  ad2[n] = sd;
}

// ---- L2 agg: same structure, 1 head, writes final out ----------------------
__global__ __launch_bounds__(512, 4) void k_l2_aggs(
    const int* __restrict__ bcnt, const unsigned int* __restrict__ pairs,
    const float* __restrict__ h2, const float* __restrict__ ad2,
    const float* __restrict__ b2, float* __restrict__ out) {
  __shared__ int cnt8[8][BW];
  __shared__ int wb[8][BW];
  __shared__ int offs[BW];
  __shared__ int tot[BW];
  __shared__ int scanbuf[BW];
  __shared__ unsigned int sorted[BCAP];
  __shared__ float partial[3 * BW * 13];
  __shared__ float biasS[10];
  int t = threadIdx.x;
  int w = t >> 6;
  int b = blockIdx.x;
  int base_n = b << BSH;
  int nloc = NN - base_n < BW ? NN - base_n : BW;
  for (int i = t; i < 8 * BW; i += 512) (&cnt8[0][0])[i] = 0;
  if (t < 10) biasS[t] = b2[t];
  __syncthreads();
  int cntb = bcnt[b];
  cntb = cntb > BCAP ? BCAP : cntb;
  const unsigned int* pp = pairs + (size_t)b * BCAP;
  for (int k = t; k < cntb; k += 512)
    atomicAdd(&cnt8[w][pp[k] & (BW - 1)], 1);
  __syncthreads();
  if (t < BW) {
    int tt = 0;
#pragma unroll
    for (int j = 0; j < 8; j++) tt += cnt8[j][t];
    tot[t] = tt;
    scanbuf[t] = tt;
  }
  __syncthreads();
  for (int step = 1; step < BW; step <<= 1) {
    int v = 0;
    if (t < BW && t >= step) v = scanbuf[t - step];
    __syncthreads();
    if (t < BW) scanbuf[t] += v;
    __syncthreads();
  }
  if (t < BW) {
    int run = scanbuf[t] - tot[t];
    offs[t] = run;
#pragma unroll
    for (int j = 0; j < 8; j++) { wb[j][t] = run; run += cnt8[j][t]; cnt8[j][t] = 0; }
  }
  __syncthreads();
  for (int k = t; k < cntb; k += 512) {
    unsigned int e = pp[k];
    int dl = e & (BW - 1);
    int pos = wb[w][dl] + atomicAdd(&cnt8[w][dl], 1);
    sorted[pos] = e >> BSH;
  }
  __syncthreads();
  int node = t & (BW - 1);
  int part = t >> 7;
  bool valid = node < nloc;
  int n = base_n + node;
  float acc[10];
#pragma unroll
  for (int j = 0; j < 10; j++) acc[j] = 0.f;
  float den = 0.f;
  float adn = valid ? ad2[n] : 0.f;
  int s0i = offs[node], c = valid ? tot[node] : 0;
  for (int k = part; k < c; k += 4) {
    int s = (int)sorted[s0i + k];
    const float4* hs = (const float4*)(h2 + (size_t)s * 16);
    float4 r0 = hs[0], r1 = hs[1], r2 = hs[2];
    float ee = r2.z + adn; ee = ee > 0.f ? ee : 0.2f * ee;
    float xv = expf(ee);
    acc[0] += xv * r0.x;  acc[1] += xv * r0.y;  acc[2] += xv * r0.z;
    acc[3] += xv * r0.w;  acc[4] += xv * r1.x;  acc[5] += xv * r1.y;
    acc[6] += xv * r1.z;  acc[7] += xv * r1.w;  acc[8] += xv * r2.x;
    acc[9] += xv * r2.y;
    den += xv;
  }
  if (part > 0) {
    float* pr = &partial[((part - 1) * BW + node) * 13];
#pragma unroll
    for (int j = 0; j < 10; j++) pr[j] = acc[j];
    pr[10] = den;
  }
  __syncthreads();
  if (part == 0 && valid) {
#pragma unroll
    for (int p = 0; p < 3; p++) {
      const float* pr = &partial[(p * BW + node) * 13];
#pragma unroll
      for (int j = 0; j < 10; j++) acc[j] += pr[j];
      den += pr[10];
    }
    const float4* hs = (const float4*)(h2 + (size_t)n * 16);  // self-loop
    float4 r0 = hs[0], r1 = hs[1], r2 = hs[2];
    float ee = r2.z + adn; ee = ee > 0.f ? ee : 0.2f * ee;
    float xv = expf(ee);
    acc[0] += xv * r0.x;  acc[1] += xv * r0.y;  acc[2] += xv * r0.z;
    acc[3] += xv * r0.w;  acc[4] += xv * r1.x;  acc[5] += xv * r1.y;
    acc[6] += xv * r1.z;  acc[7] += xv * r1.w;  acc[8] += xv * r2.x;
    acc[9] += xv * r2.y;
    den += xv;
    float inv = 1.f / (den + 1e-16f);
    float2* orow = (float2*)(out + (size_t)n * 10);
    orow[0] = make_float2(acc[0] * inv + biasS[0], acc[1] * inv + biasS[1]);
    orow[1] = make_float2(acc[2] * inv + biasS[2], acc[3] * inv + biasS[3]);
    orow[2] = make_float2(acc[4] * inv + biasS[4], acc[5] * inv + biasS[5]);
    orow[3] = make_float2(acc[6] * inv + biasS[6], acc[7] * inv + biasS[7]);
    orow[4] = make_float2(acc[8] * inv + biasS[8], acc[9] * inv + biasS[9]);
  }
}

extern "C" void kernel_launch(void* const* d_in, const int* in_sizes, int n_in,
                              void* d_out, int out_size, void* d_ws, size_t ws_size,
                              hipStream_t stream) {
  const float* x      = (const float*)d_in[0];
  const float* W1     = (const float*)d_in[1];
  const float* a_src1 = (const float*)d_in[2];
  const float* a_dst1 = (const float*)d_in[3];
  const float* b1     = (const float*)d_in[4];
  const float* gamma1 = (const float*)d_in[5];
  const float* beta1  = (const float*)d_in[6];
  const float* W2     = (const float*)d_in[7];
  const float* a_src2 = (const float*)d_in[8];
  const float* a_dst2 = (const float*)d_in[9];
  const float* b2     = (const float*)d_in[10];
  const int*   ei     = (const int*)d_in[11];
  float* out = (float*)d_out;

  // Workspace layout (4B units), ~47.8 MB total (72 MB proven available).
  int* bcnt = (int*)d_ws;                               // NBKT (zeroed)
  unsigned int* pairs = (unsigned int*)d_ws + 1024;     // NBKT*BCAP
  float* h1 = (float*)(pairs + (size_t)NBKT * BCAP);    // NN*16
  float* ad1 = h1 + (size_t)NN * 16;                    // NN*2
  float* g1 = ad1 + (size_t)NN * 2;                     // NN*12
  float* h2 = g1 + (size_t)NN * 12;                     // NN*16
  float* ad2 = h2 + (size_t)NN * 16;                    // NN
  float* bn_part = ad2 + NN;                            // 20*BNP (fully written)
  float* bns = bn_part + 20 * BNP;                      // 20 (written by k_bnred)

  hipMemsetAsync(d_ws, 0, 4096, stream);  // bcnt

  const int B = 256;
  const int gN = (NN + B - 1) / B;               // 391
  const int gBin = (NE + BIN_CH - 1) / BIN_CH;   // 782

  k_bin<<<gBin, B, 0, stream>>>(ei, bcnt, pairs);
  k_l1_node<<<gN, B, 0, stream>>>(x, W1, a_src1, a_dst1, h1, (float2*)ad1);
  k_l1_aggs<<<NBKT, 512, 0, stream>>>(bcnt, pairs, h1, (const float2*)ad1, b1,
                                      g1, bn_part);
  k_bnred<<<20, 64, 0, stream>>>(bn_part, bns);
  k_l2_node<<<gN, B, 0, stream>>>(g1, bns, gamma1, beta1, W2, a_src2, a_dst2,
                                  h2, ad2);
  k_l2_aggs<<<NBKT, 512, 0, stream>>>(bcnt, pairs, h2, ad2, b2, out);
}

// Round 8
// 453.825 us; speedup vs baseline: 3.5226x; 1.0302x over previous
//
#include <hip/hip_runtime.h>
#include <math.h>

#define NN 100000
#define NE 6400000
#define INCH 128
#define BSH 7                       // bucket = 128 dst nodes
#define BW (1 << BSH)
#define NBKT ((NN + BW - 1) / BW)   // 782
#define NBP 784                     // padded row stride for cntmat/basemat
#define BCAP 9216                   // slots/bucket (mean 8192, +11 sigma)
#define BIN_CH 8192                 // edges per bin block
#define BNP 800                     // bn_part column stride (>= NBKT)

// ---- Phase 1: per-chunk bucket histogram -> dense cntmat (no atomics) ------
__global__ __launch_bounds__(256) void k_count(const int* __restrict__ ei,
                                               int* __restrict__ cntmat) {
  __shared__ int cnt4[4][NBKT];
  int t = threadIdx.x;
  int w = t >> 6;
  for (int i = t; i < 4 * NBKT; i += 256) (&cnt4[0][0])[i] = 0;
  __syncthreads();
  int c0 = blockIdx.x * BIN_CH;
  int c1 = c0 + BIN_CH < NE ? c0 + BIN_CH : NE;
  for (int i = c0 + t; i < c1; i += 256)
    atomicAdd(&cnt4[w][ei[NE + i] >> BSH], 1);
  __syncthreads();
  for (int b = t; b < NBKT; b += 256)
    cntmat[(size_t)b * NBP + blockIdx.x] =
        cnt4[0][b] + cnt4[1][b] + cnt4[2][b] + cnt4[3][b];
}

// ---- Phase 2: per-bucket prefix over chunks (wave scan, no atomics) --------
__global__ __launch_bounds__(64) void k_scanb(const int* __restrict__ cntmat,
                                              int* __restrict__ basemat,
                                              int* __restrict__ bcnt) {
  int j = blockIdx.x;  // bucket
  int lane = threadIdx.x;
  int carry = 0;
  for (int i0 = 0; i0 < NBKT; i0 += 64) {
    int i = i0 + lane;
    int v0 = (i < NBKT) ? cntmat[(size_t)j * NBP + i] : 0;
    int v = v0;
#pragma unroll
    for (int off = 1; off < 64; off <<= 1) {
      int u = __shfl_up(v, off, 64);
      if (lane >= off) v += u;
    }
    if (i < NBKT) basemat[(size_t)i * NBP + j] = carry + v - v0;  // exclusive
    carry += __shfl(v, 63, 64);  // chunk total, uniform
  }
  if (lane == 0) bcnt[j] = carry;
}

// ---- Phase 3: LDS-staged counting sort, coalesced flush, bases precomputed -
// Entry packing: (src << 7) | (dst & 127)  -- 24 bits used.
__global__ __launch_bounds__(256) void k_scatter2(
    const int* __restrict__ ei, const int* __restrict__ basemat,
    unsigned int* __restrict__ pairs) {
  __shared__ int cnt4[4][NBKT];        // per-wave private counts
  __shared__ int wb4[4][NBKT];         // per-wave LDS staging cursors
  __shared__ int offs[NBKT + 1];       // staging exclusive offsets (+sentinel)
  __shared__ int gbase[NBKT];          // global base per bucket (precomputed)
  __shared__ int scanp[256];
  __shared__ unsigned int stage[BIN_CH];
  int t = threadIdx.x;
  int w = t >> 6;
  for (int i = t; i < 4 * NBKT; i += 256) (&cnt4[0][0])[i] = 0;
  for (int b = t; b < NBKT; b += 256)
    gbase[b] = basemat[(size_t)blockIdx.x * NBP + b];  // coalesced, no atomic
  __syncthreads();
  int c0 = blockIdx.x * BIN_CH;
  int c1 = c0 + BIN_CH < NE ? c0 + BIN_CH : NE;
  // pass A: per-wave histogram of dst buckets
  for (int i = c0 + t; i < c1; i += 256)
    atomicAdd(&cnt4[w][ei[NE + i] >> BSH], 1);
  __syncthreads();
  // block-level exclusive scan over 782 bucket totals (4 buckets/thread)
  int myb0 = t * 4;
  int tots[4];
  int asum = 0;
#pragma unroll
  for (int j = 0; j < 4; j++) {
    int b = myb0 + j;
    int tt = (b < NBKT) ? cnt4[0][b] + cnt4[1][b] + cnt4[2][b] + cnt4[3][b] : 0;
    tots[j] = tt;
    asum += tt;
  }
  scanp[t] = asum;
  __syncthreads();
  for (int off = 1; off < 256; off <<= 1) {
    int v = (t >= off) ? scanp[t - off] : 0;
    __syncthreads();
    scanp[t] += v;
    __syncthreads();
  }
  int run = (t == 0) ? 0 : scanp[t - 1];
#pragma unroll
  for (int j = 0; j < 4; j++) {
    int b = myb0 + j;
    if (b < NBKT) {
      int tt = tots[j];
      offs[b] = run;
      wb4[0][b] = run;
      wb4[1][b] = run + cnt4[0][b];
      wb4[2][b] = wb4[1][b] + cnt4[1][b];
      wb4[3][b] = wb4[2][b] + cnt4[2][b];
      run += tt;
    }
  }
  if (t == 255) offs[NBKT] = scanp[255];  // sentinel = chunk size
  __syncthreads();
  // pass B: scatter packed entries into LDS staging (bucket-grouped)
  for (int i = c0 + t; i < c1; i += 256) {
    int s = ei[i], d = ei[NE + i];
    int bkt = d >> BSH;
    int pos = atomicAdd(&wb4[w][bkt], 1);
    stage[pos] = ((unsigned int)s << BSH) | (unsigned int)(d & (BW - 1));
  }
  __syncthreads();
  // flush: consecutive threads -> consecutive global addrs within bucket runs
  int total = offs[NBKT];
  for (int i = t; i < total; i += 256) {
    unsigned int e = stage[i];
    int lo = 0, hi = NBKT - 1;  // largest b with offs[b] <= i
    while (lo < hi) {
      int mid = (lo + hi + 1) >> 1;
      if (offs[mid] <= i) lo = mid; else hi = mid - 1;
    }
    int gp = gbase[lo] + (i - offs[lo]);
    if (gp < BCAP) pairs[(size_t)lo * BCAP + gp] = e;
  }
}

// ---------------- Layer 1 node: h1 = x@W1; src logits embedded --------------
// h1 row (stride 16): [h0..h9, -, -, as_x, as_y at r2.z/.w]; ad1 separate.
__global__ __launch_bounds__(256) void k_l1_node(
    const float* __restrict__ x, const float* __restrict__ W1,
    const float* __restrict__ a_src1, const float* __restrict__ a_dst1,
    float* __restrict__ h1, float2* __restrict__ ad1) {
  __shared__ float Wt[10 * INCH];
  __shared__ float asw[10], adw[10];
  for (int i = threadIdx.x; i < 10 * INCH; i += blockDim.x) {
    int c = i / 10, k = i - c * 10;
    Wt[k * INCH + c] = W1[i];
  }
  if (threadIdx.x < 10) {
    asw[threadIdx.x] = a_src1[threadIdx.x];
    adw[threadIdx.x] = a_dst1[threadIdx.x];
  }
  __syncthreads();
  int n = blockIdx.x * blockDim.x + threadIdx.x;
  if (n >= NN) return;
  const float4* xr = (const float4*)(x + (size_t)n * INCH);
  const float4* Wt4 = (const float4*)Wt;
  float acc[10];
#pragma unroll
  for (int k = 0; k < 10; k++) acc[k] = 0.f;
#pragma unroll 8
  for (int c4 = 0; c4 < INCH / 4; c4++) {
    float4 xv = xr[c4];
#pragma unroll
    for (int k = 0; k < 10; k++) {
      float4 wv = Wt4[k * (INCH / 4) + c4];
      acc[k] += xv.x * wv.x + xv.y * wv.y + xv.z * wv.z + xv.w * wv.w;
    }
  }
  float s0 = 0.f, s1 = 0.f, d0 = 0.f, d1 = 0.f;
#pragma unroll
  for (int j = 0; j < 5; j++) {
    s0 += acc[j] * asw[j];
    s1 += acc[5 + j] * asw[5 + j];
    d0 += acc[j] * adw[j];
    d1 += acc[5 + j] * adw[5 + j];
  }
  float4* hrow = (float4*)(h1 + (size_t)n * 16);
  hrow[0] = make_float4(acc[0], acc[1], acc[2], acc[3]);
  hrow[1] = make_float4(acc[4], acc[5], acc[6], acc[7]);
  hrow[2] = make_float4(acc[8], acc[9], s0, s1);
  ad1[n] = make_float2(d0, d1);
}

// ---- L1 agg: LDS counting sort, 4 threads/node reg accumulation, BN fused --
__global__ __launch_bounds__(512, 4) void k_l1_aggs(
    const int* __restrict__ bcnt, const unsigned int* __restrict__ pairs,
    const float* __restrict__ h1, const float2* __restrict__ ad1,
    const float* __restrict__ b1, float* __restrict__ g1,
    float* __restrict__ bn_part) {
  __shared__ int cnt8[8][BW];        // per-wave counts / cursors
  __shared__ int wb[8][BW];          // per-wave scatter base
  __shared__ int offs[BW];
  __shared__ int tot[BW];
  __shared__ int scanbuf[BW];
  __shared__ unsigned int sorted[BCAP];
  __shared__ float partial[3 * BW * 13];  // parts 1..3
  __shared__ float biasS[10];
  __shared__ float bn_lds[40];
  int t = threadIdx.x;
  int w = t >> 6;
  int b = blockIdx.x;
  int base_n = b << BSH;
  int nloc = NN - base_n < BW ? NN - base_n : BW;
  for (int i = t; i < 8 * BW; i += 512) (&cnt8[0][0])[i] = 0;
  if (t < 10) biasS[t] = b1[t];
  __syncthreads();
  int cntb = bcnt[b];
  cntb = cntb > BCAP ? BCAP : cntb;
  const unsigned int* pp = pairs + (size_t)b * BCAP;
  for (int k = t; k < cntb; k += 512)
    atomicAdd(&cnt8[w][pp[k] & (BW - 1)], 1);
  __syncthreads();
  if (t < BW) {
    int tt = 0;
#pragma unroll
    for (int j = 0; j < 8; j++) tt += cnt8[j][t];
    tot[t] = tt;
    scanbuf[t] = tt;
  }
  __syncthreads();
  for (int step = 1; step < BW; step <<= 1) {  // Hillis-Steele inclusive scan
    int v = 0;
    if (t < BW && t >= step) v = scanbuf[t - step];
    __syncthreads();
    if (t < BW) scanbuf[t] += v;
    __syncthreads();
  }
  if (t < BW) {
    int run = scanbuf[t] - tot[t];
    offs[t] = run;
#pragma unroll
    for (int j = 0; j < 8; j++) { wb[j][t] = run; run += cnt8[j][t]; cnt8[j][t] = 0; }
  }
  __syncthreads();
  for (int k = t; k < cntb; k += 512) {
    unsigned int e = pp[k];
    int dl = e & (BW - 1);
    int pos = wb[w][dl] + atomicAdd(&cnt8[w][dl], 1);
    sorted[pos] = e >> BSH;
  }
  __syncthreads();
  // phase 4: 4 threads per node, serial register accumulation
  int node = t & (BW - 1);
  int part = t >> 7;  // 0..3 (wave-uniform pairs)
  bool valid = node < nloc;
  int n = base_n + node;
  float acc[10];
#pragma unroll
  for (int j = 0; j < 10; j++) acc[j] = 0.f;
  float den0 = 0.f, den1 = 0.f;
  float2 adn = valid ? ad1[n] : make_float2(0.f, 0.f);
  int s0i = offs[node], c = valid ? tot[node] : 0;
  for (int k = part; k < c; k += 4) {
    int s = (int)sorted[s0i + k];
    const float4* hs = (const float4*)(h1 + (size_t)s * 16);
    float4 r0 = hs[0], r1 = hs[1], r2 = hs[2];
    float e0 = r2.z + adn.x; e0 = e0 > 0.f ? e0 : 0.2f * e0;
    float e1 = r2.w + adn.y; e1 = e1 > 0.f ? e1 : 0.2f * e1;
    float x0 = expf(e0), x1 = expf(e1);
    acc[0] += x0 * r0.x;  acc[1] += x0 * r0.y;  acc[2] += x0 * r0.z;
    acc[3] += x0 * r0.w;  acc[4] += x0 * r1.x;
    acc[5] += x1 * r1.y;  acc[6] += x1 * r1.z;  acc[7] += x1 * r1.w;
    acc[8] += x1 * r2.x;  acc[9] += x1 * r2.y;
    den0 += x0; den1 += x1;
  }
  if (part > 0) {
    float* pr = &partial[((part - 1) * BW + node) * 13];
#pragma unroll
    for (int j = 0; j < 10; j++) pr[j] = acc[j];
    pr[10] = den0; pr[11] = den1;
  }
  __syncthreads();
  if (part == 0) {  // waves 0,1
    float v[10];
    if (valid) {
#pragma unroll
      for (int p = 0; p < 3; p++) {
        const float* pr = &partial[(p * BW + node) * 13];
#pragma unroll
        for (int j = 0; j < 10; j++) acc[j] += pr[j];
        den0 += pr[10]; den1 += pr[11];
      }
      // self-loop (src == dst == n)
      const float4* hs = (const float4*)(h1 + (size_t)n * 16);
      float4 r0 = hs[0], r1 = hs[1], r2 = hs[2];
      float e0 = r2.z + adn.x; e0 = e0 > 0.f ? e0 : 0.2f * e0;
      float e1 = r2.w + adn.y; e1 = e1 > 0.f ? e1 : 0.2f * e1;
      float x0 = expf(e0), x1 = expf(e1);
      acc[0] += x0 * r0.x;  acc[1] += x0 * r0.y;  acc[2] += x0 * r0.z;
      acc[3] += x0 * r0.w;  acc[4] += x0 * r1.x;
      acc[5] += x1 * r1.y;  acc[6] += x1 * r1.z;  acc[7] += x1 * r1.w;
      acc[8] += x1 * r2.x;  acc[9] += x1 * r2.y;
      den0 += x0; den1 += x1;
      float i0 = 1.f / (den0 + 1e-16f), i1 = 1.f / (den1 + 1e-16f);
#pragma unroll
      for (int j = 0; j < 5; j++) v[j] = acc[j] * i0 + biasS[j];
#pragma unroll
      for (int j = 5; j < 10; j++) v[j] = acc[j] * i1 + biasS[j];
      float4* gr = (float4*)(g1 + (size_t)n * 12);
      gr[0] = make_float4(v[0], v[1], v[2], v[3]);
      gr[1] = make_float4(v[4], v[5], v[6], v[7]);
      gr[2] = make_float4(v[8], v[9], 0.f, 0.f);
    } else {
#pragma unroll
      for (int j = 0; j < 10; j++) v[j] = 0.f;
    }
    // BN partials: reduce 20 quantities across each of waves 0,1
    float s[20];
#pragma unroll
    for (int j = 0; j < 10; j++) { s[j] = v[j]; s[10 + j] = v[j] * v[j]; }
#pragma unroll
    for (int j = 0; j < 20; j++) {
      for (int off = 32; off > 0; off >>= 1) s[j] += __shfl_down(s[j], off, 64);
    }
    if ((t & 63) == 0) {
#pragma unroll
      for (int j = 0; j < 20; j++) bn_lds[w * 20 + j] = s[j];
    }
  }
  __syncthreads();
  if (t == 0) {
#pragma unroll
    for (int j = 0; j < 20; j++)
      bn_part[j * BNP + b] = bn_lds[j] + bn_lds[20 + j];  // unique slot, no atomic
  }
}

// ---- BN final reduce: one block per channel-stat, no contended atomics -----
__global__ __launch_bounds__(64) void k_bnred(const float* __restrict__ bn_part,
                                              float* __restrict__ bns) {
  int j = blockIdx.x;  // 0..19
  int lane = threadIdx.x;
  float s = 0.f;
  for (int b = lane; b < NBKT; b += 64) s += bn_part[j * BNP + b];
#pragma unroll
  for (int off = 32; off > 0; off >>= 1) s += __shfl_down(s, off, 64);
  if (lane == 0) bns[j] = s;
}

// -------- Layer 2 node: BN + ELU + h2 = hn@W2; as2 embedded at r2.z ---------
__global__ __launch_bounds__(256) void k_l2_node(
    const float* __restrict__ g1, const float* __restrict__ bns,
    const float* __restrict__ gamma1, const float* __restrict__ beta1,
    const float* __restrict__ W2, const float* __restrict__ a_src2,
    const float* __restrict__ a_dst2, float* __restrict__ h2,
    float* __restrict__ ad2) {
  __shared__ float scale[10], shift[10], W2s[100], a2s[10], a2d[10];
  if (threadIdx.x < 10) {
    int j = threadIdx.x;
    float mu = bns[j] * (1.f / NN);
    float var = bns[10 + j] * (1.f / NN) - mu * mu;
    float rs = rsqrtf(var + 1e-5f);
    scale[j] = rs * gamma1[j];
    shift[j] = beta1[j] - mu * rs * gamma1[j];
    a2s[j] = a_src2[j];
    a2d[j] = a_dst2[j];
  }
  for (int i = threadIdx.x; i < 100; i += blockDim.x) W2s[i] = W2[i];
  __syncthreads();
  int n = blockIdx.x * blockDim.x + threadIdx.x;
  if (n >= NN) return;
  const float4* gr = (const float4*)(g1 + (size_t)n * 12);
  float4 g0 = gr[0], g1v = gr[1], g2 = gr[2];
  float hv[10] = {g0.x, g0.y, g0.z, g0.w, g1v.x, g1v.y, g1v.z, g1v.w, g2.x, g2.y};
#pragma unroll
  for (int j = 0; j < 10; j++) {
    float t = hv[j] * scale[j] + shift[j];
    hv[j] = t > 0.f ? t : expm1f(t);  // ELU
  }
  float o[10];
#pragma unroll
  for (int k = 0; k < 10; k++) o[k] = 0.f;
#pragma unroll
  for (int c = 0; c < 10; c++) {
#pragma unroll
    for (int k = 0; k < 10; k++) o[k] += hv[c] * W2s[c * 10 + k];
  }
  float ss = 0.f, sd = 0.f;
#pragma unroll
  for (int k = 0; k < 10; k++) { ss += o[k] * a2s[k]; sd += o[k] * a2d[k]; }
  float4* hr = (float4*)(h2 + (size_t)n * 16);
  hr[0] = make_float4(o[0], o[1], o[2], o[3]);
  hr[1] = make_float4(o[4], o[5], o[6], o[7]);
  hr[2] = make_float4(o[8], o[9], ss, 0.f);
  ad2[n] = sd;
}

// ---- L2 agg: same structure, 1 head, writes final out ----------------------
__global__ __launch_bounds__(512, 4) void k_l2_aggs(
    const int* __restrict__ bcnt, const unsigned int* __restrict__ pairs,
    const float* __restrict__ h2, const float* __restrict__ ad2,
    const float* __restrict__ b2, float* __restrict__ out) {
  __shared__ int cnt8[8][BW];
  __shared__ int wb[8][BW];
  __shared__ int offs[BW];
  __shared__ int tot[BW];
  __shared__ int scanbuf[BW];
  __shared__ unsigned int sorted[BCAP];
  __shared__ float partial[3 * BW * 13];
  __shared__ float biasS[10];
  int t = threadIdx.x;
  int w = t >> 6;
  int b = blockIdx.x;
  int base_n = b << BSH;
  int nloc = NN - base_n < BW ? NN - base_n : BW;
  for (int i = t; i < 8 * BW; i += 512) (&cnt8[0][0])[i] = 0;
  if (t < 10) biasS[t] = b2[t];
  __syncthreads();
  int cntb = bcnt[b];
  cntb = cntb > BCAP ? BCAP : cntb;
  const unsigned int* pp = pairs + (size_t)b * BCAP;
  for (int k = t; k < cntb; k += 512)
    atomicAdd(&cnt8[w][pp[k] & (BW - 1)], 1);
  __syncthreads();
  if (t < BW) {
    int tt = 0;
#pragma unroll
    for (int j = 0; j < 8; j++) tt += cnt8[j][t];
    tot[t] = tt;
    scanbuf[t] = tt;
  }
  __syncthreads();
  for (int step = 1; step < BW; step <<= 1) {
    int v = 0;
    if (t < BW && t >= step) v = scanbuf[t - step];
    __syncthreads();
    if (t < BW) scanbuf[t] += v;
    __syncthreads();
  }
  if (t < BW) {
    int run = scanbuf[t] - tot[t];
    offs[t] = run;
#pragma unroll
    for (int j = 0; j < 8; j++) { wb[j][t] = run; run += cnt8[j][t]; cnt8[j][t] = 0; }
  }
  __syncthreads();
  for (int k = t; k < cntb; k += 512) {
    unsigned int e = pp[k];
    int dl = e & (BW - 1);
    int pos = wb[w][dl] + atomicAdd(&cnt8[w][dl], 1);
    sorted[pos] = e >> BSH;
  }
  __syncthreads();
  int node = t & (BW - 1);
  int part = t >> 7;
  bool valid = node < nloc;
  int n = base_n + node;
  float acc[10];
#pragma unroll
  for (int j = 0; j < 10; j++) acc[j] = 0.f;
  float den = 0.f;
  float adn = valid ? ad2[n] : 0.f;
  int s0i = offs[node], c = valid ? tot[node] : 0;
  for (int k = part; k < c; k += 4) {
    int s = (int)sorted[s0i + k];
    const float4* hs = (const float4*)(h2 + (size_t)s * 16);
    float4 r0 = hs[0], r1 = hs[1], r2 = hs[2];
    float ee = r2.z + adn; ee = ee > 0.f ? ee : 0.2f * ee;
    float xv = expf(ee);
    acc[0] += xv * r0.x;  acc[1] += xv * r0.y;  acc[2] += xv * r0.z;
    acc[3] += xv * r0.w;  acc[4] += xv * r1.x;  acc[5] += xv * r1.y;
    acc[6] += xv * r1.z;  acc[7] += xv * r1.w;  acc[8] += xv * r2.x;
    acc[9] += xv * r2.y;
    den += xv;
  }
  if (part > 0) {
    float* pr = &partial[((part - 1) * BW + node) * 13];
#pragma unroll
    for (int j = 0; j < 10; j++) pr[j] = acc[j];
    pr[10] = den;
  }
  __syncthreads();
  if (part == 0 && valid) {
#pragma unroll
    for (int p = 0; p < 3; p++) {
      const float* pr = &partial[(p * BW + node) * 13];
#pragma unroll
      for (int j = 0; j < 10; j++) acc[j] += pr[j];
      den += pr[10];
    }
    const float4* hs = (const float4*)(h2 + (size_t)n * 16);  // self-loop
    float4 r0 = hs[0], r1 = hs[1], r2 = hs[2];
    float ee = r2.z + adn; ee = ee > 0.f ? ee : 0.2f * ee;
    float xv = expf(ee);
    acc[0] += xv * r0.x;  acc[1] += xv * r0.y;  acc[2] += xv * r0.z;
    acc[3] += xv * r0.w;  acc[4] += xv * r1.x;  acc[5] += xv * r1.y;
    acc[6] += xv * r1.z;  acc[7] += xv * r1.w;  acc[8] += xv * r2.x;
    acc[9] += xv * r2.y;
    den += xv;
    float inv = 1.f / (den + 1e-16f);
    float2* orow = (float2*)(out + (size_t)n * 10);
    orow[0] = make_float2(acc[0] * inv + biasS[0], acc[1] * inv + biasS[1]);
    orow[1] = make_float2(acc[2] * inv + biasS[2], acc[3] * inv + biasS[3]);
    orow[2] = make_float2(acc[4] * inv + biasS[4], acc[5] * inv + biasS[5]);
    orow[3] = make_float2(acc[6] * inv + biasS[6], acc[7] * inv + biasS[7]);
    orow[4] = make_float2(acc[8] * inv + biasS[8], acc[9] * inv + biasS[9]);
  }
}

extern "C" void kernel_launch(void* const* d_in, const int* in_sizes, int n_in,
                              void* d_out, int out_size, void* d_ws, size_t ws_size,
                              hipStream_t stream) {
  const float* x      = (const float*)d_in[0];
  const float* W1     = (const float*)d_in[1];
  const float* a_src1 = (const float*)d_in[2];
  const float* a_dst1 = (const float*)d_in[3];
  const float* b1     = (const float*)d_in[4];
  const float* gamma1 = (const float*)d_in[5];
  const float* beta1  = (const float*)d_in[6];
  const float* W2     = (const float*)d_in[7];
  const float* a_src2 = (const float*)d_in[8];
  const float* a_dst2 = (const float*)d_in[9];
  const float* b2     = (const float*)d_in[10];
  const int*   ei     = (const int*)d_in[11];
  float* out = (float*)d_out;

  // Workspace layout (4B units), ~52.7 MB total (72 MB proven available).
  // All regions fully written before read -> no memset needed.
  int* bcnt = (int*)d_ws;                               // NBKT (k_scanb writes)
  unsigned int* pairs = (unsigned int*)d_ws + 1024;     // NBKT*BCAP
  float* h1 = (float*)(pairs + (size_t)NBKT * BCAP);    // NN*16
  float* ad1 = h1 + (size_t)NN * 16;                    // NN*2
  float* g1 = ad1 + (size_t)NN * 2;                     // NN*12
  float* h2 = g1 + (size_t)NN * 12;                     // NN*16
  float* ad2 = h2 + (size_t)NN * 16;                    // NN
  float* bn_part = ad2 + NN;                            // 20*BNP
  float* bns = bn_part + 20 * BNP;                      // 20
  int* cntmat = (int*)(bns + 20 + 12);                  // NBKT*NBP
  int* basemat = cntmat + (size_t)NBKT * NBP;           // NBKT*NBP

  const int B = 256;
  const int gN = (NN + B - 1) / B;               // 391
  const int gBin = (NE + BIN_CH - 1) / BIN_CH;   // 782

  k_count<<<gBin, B, 0, stream>>>(ei, cntmat);
  k_scanb<<<NBKT, 64, 0, stream>>>(cntmat, basemat, bcnt);
  k_scatter2<<<gBin, B, 0, stream>>>(ei, basemat, pairs);
  k_l1_node<<<gN, B, 0, stream>>>(x, W1, a_src1, a_dst1, h1, (float2*)ad1);
  k_l1_aggs<<<NBKT, 512, 0, stream>>>(bcnt, pairs, h1, (const float2*)ad1, b1,
                                      g1, bn_part);
  k_bnred<<<20, 64, 0, stream>>>(bn_part, bns);
  k_l2_node<<<gN, B, 0, stream>>>(g1, bns, gamma1, beta1, W2, a_src2, a_dst2,
                                  h2, ad2);
  k_l2_aggs<<<NBKT, 512, 0, stream>>>(bcnt, pairs, h2, ad2, b2, out);
}

// Round 9
// 410.271 us; speedup vs baseline: 3.8966x; 1.1062x over previous
//
#include <hip/hip_runtime.h>
#include <math.h>

#define NN 100000
#define NE 6400000
#define INCH 128
#define BSH 7                       // bucket = 128 dst nodes
#define BW (1 << BSH)
#define NBKT ((NN + BW - 1) / BW)   // 782
#define NBP 784                     // padded row stride for cntmat/basemat
#define BCAP 9216                   // slots/bucket (mean 8192, +11 sigma)
#define BIN_CH 8192                 // edges per bin block
#define BNP 800                     // bn_part column stride (>= NBKT)

// ---- Phase 1: per-chunk bucket histogram -> dense cntmat (no atomics) ------
__global__ __launch_bounds__(256) void k_count(const int* __restrict__ ei,
                                               int* __restrict__ cntmat) {
  __shared__ int cnt4[4][NBKT];
  int t = threadIdx.x;
  int w = t >> 6;
  for (int i = t; i < 4 * NBKT; i += 256) (&cnt4[0][0])[i] = 0;
  __syncthreads();
  int c0 = blockIdx.x * BIN_CH;
  int c1 = c0 + BIN_CH < NE ? c0 + BIN_CH : NE;
  for (int i = c0 + t; i < c1; i += 256)
    atomicAdd(&cnt4[w][ei[NE + i] >> BSH], 1);
  __syncthreads();
  for (int b = t; b < NBKT; b += 256)
    cntmat[(size_t)b * NBP + blockIdx.x] =
        cnt4[0][b] + cnt4[1][b] + cnt4[2][b] + cnt4[3][b];
}

// ---- Phase 2: per-bucket prefix over chunks (wave scan, no atomics) --------
__global__ __launch_bounds__(64) void k_scanb(const int* __restrict__ cntmat,
                                              int* __restrict__ basemat,
                                              int* __restrict__ bcnt) {
  int j = blockIdx.x;  // bucket
  int lane = threadIdx.x;
  int carry = 0;
  for (int i0 = 0; i0 < NBKT; i0 += 64) {
    int i = i0 + lane;
    int v0 = (i < NBKT) ? cntmat[(size_t)j * NBP + i] : 0;
    int v = v0;
#pragma unroll
    for (int off = 1; off < 64; off <<= 1) {
      int u = __shfl_up(v, off, 64);
      if (lane >= off) v += u;
    }
    if (i < NBKT) basemat[(size_t)i * NBP + j] = carry + v - v0;  // exclusive
    carry += __shfl(v, 63, 64);  // chunk total, uniform
  }
  if (lane == 0) bcnt[j] = carry;
}

// ---- Phase 3: LDS-staged counting sort; hist read from cntmat; no search ---
// Entry packing: (src << 7) | (dst & 127)  -- 24 bits used.
__global__ __launch_bounds__(256) void k_scatter2(
    const int* __restrict__ ei, const int* __restrict__ cntmat,
    const int* __restrict__ basemat, unsigned int* __restrict__ pairs) {
  __shared__ int offs[NBKT];           // staging exclusive offsets
  __shared__ int cur[NBKT];            // shared cursors (low contention)
  __shared__ int gbase[NBKT];          // global base per bucket (precomputed)
  __shared__ int scanp[256];
  __shared__ unsigned int stage[BIN_CH];
  __shared__ unsigned short sbkt[BIN_CH];  // bucket id per staged entry
  int t = threadIdx.x;
  int chunk = blockIdx.x;
  // load chunk histogram (cntmat column) + global bases (coalesced row)
  int myb0 = t * 4;
  int tots[4];
  int asum = 0;
#pragma unroll
  for (int j = 0; j < 4; j++) {
    int b = myb0 + j;
    int tt = (b < NBKT) ? cntmat[(size_t)b * NBP + chunk] : 0;
    tots[j] = tt;
    asum += tt;
  }
  for (int b = t; b < NBKT; b += 256)
    gbase[b] = basemat[(size_t)chunk * NBP + b];
  scanp[t] = asum;
  __syncthreads();
  for (int off = 1; off < 256; off <<= 1) {
    int v = (t >= off) ? scanp[t - off] : 0;
    __syncthreads();
    scanp[t] += v;
    __syncthreads();
  }
  int run = (t == 0) ? 0 : scanp[t - 1];
#pragma unroll
  for (int j = 0; j < 4; j++) {
    int b = myb0 + j;
    if (b < NBKT) {
      offs[b] = run;
      cur[b] = run;
      run += tots[j];
    }
  }
  __syncthreads();
  // stage: scatter packed entries into LDS (bucket-grouped) + bucket ids
  int c0 = chunk * BIN_CH;
  int c1 = c0 + BIN_CH < NE ? c0 + BIN_CH : NE;
  for (int i = c0 + t; i < c1; i += 256) {
    int s = ei[i], d = ei[NE + i];
    int bkt = d >> BSH;
    int pos = atomicAdd(&cur[bkt], 1);
    stage[pos] = ((unsigned int)s << BSH) | (unsigned int)(d & (BW - 1));
    sbkt[pos] = (unsigned short)bkt;
  }
  __syncthreads();
  // flush: consecutive threads -> consecutive global addrs within bucket runs
  int total = c1 - c0;
  for (int i = t; i < total; i += 256) {
    unsigned int e = stage[i];
    int b = sbkt[i];
    int gp = gbase[b] + (i - offs[b]);
    if (gp < BCAP) pairs[(size_t)b * BCAP + gp] = e;
  }
}

// ---------------- Layer 1 node: h1 = x@W1; src logits embedded --------------
// h1 row (stride 16): [h0..h9, -, -, as_x, as_y at r2.z/.w]; ad1 separate.
__global__ __launch_bounds__(256) void k_l1_node(
    const float* __restrict__ x, const float* __restrict__ W1,
    const float* __restrict__ a_src1, const float* __restrict__ a_dst1,
    float* __restrict__ h1, float2* __restrict__ ad1) {
  __shared__ float Wt[10 * INCH];
  __shared__ float asw[10], adw[10];
  for (int i = threadIdx.x; i < 10 * INCH; i += blockDim.x) {
    int c = i / 10, k = i - c * 10;
    Wt[k * INCH + c] = W1[i];
  }
  if (threadIdx.x < 10) {
    asw[threadIdx.x] = a_src1[threadIdx.x];
    adw[threadIdx.x] = a_dst1[threadIdx.x];
  }
  __syncthreads();
  int n = blockIdx.x * blockDim.x + threadIdx.x;
  if (n >= NN) return;
  const float4* xr = (const float4*)(x + (size_t)n * INCH);
  const float4* Wt4 = (const float4*)Wt;
  float acc[10];
#pragma unroll
  for (int k = 0; k < 10; k++) acc[k] = 0.f;
#pragma unroll 8
  for (int c4 = 0; c4 < INCH / 4; c4++) {
    float4 xv = xr[c4];
#pragma unroll
    for (int k = 0; k < 10; k++) {
      float4 wv = Wt4[k * (INCH / 4) + c4];
      acc[k] += xv.x * wv.x + xv.y * wv.y + xv.z * wv.z + xv.w * wv.w;
    }
  }
  float s0 = 0.f, s1 = 0.f, d0 = 0.f, d1 = 0.f;
#pragma unroll
  for (int j = 0; j < 5; j++) {
    s0 += acc[j] * asw[j];
    s1 += acc[5 + j] * asw[5 + j];
    d0 += acc[j] * adw[j];
    d1 += acc[5 + j] * adw[5 + j];
  }
  float4* hrow = (float4*)(h1 + (size_t)n * 16);
  hrow[0] = make_float4(acc[0], acc[1], acc[2], acc[3]);
  hrow[1] = make_float4(acc[4], acc[5], acc[6], acc[7]);
  hrow[2] = make_float4(acc[8], acc[9], s0, s1);
  ad1[n] = make_float2(d0, d1);
}

// ---- L1 agg: LDS counting sort; 4 adjacent lanes/node; shfl combine --------
__global__ __launch_bounds__(512, 6) void k_l1_aggs(
    const int* __restrict__ bcnt, const unsigned int* __restrict__ pairs,
    const float* __restrict__ h1, const float2* __restrict__ ad1,
    const float* __restrict__ b1, float* __restrict__ g1,
    float* __restrict__ bn_part) {
  __shared__ int cnt8[8][BW];        // per-wave counts / cursors
  __shared__ int wb[8][BW];          // per-wave scatter base
  __shared__ int offs[BW];
  __shared__ int tot[BW];
  __shared__ int scanbuf[BW];
  __shared__ unsigned int sorted[BCAP];
  __shared__ float biasS[10];
  __shared__ float bn_lds[8 * 20];
  int t = threadIdx.x;
  int w = t >> 6;
  int b = blockIdx.x;
  int base_n = b << BSH;
  int nloc = NN - base_n < BW ? NN - base_n : BW;
  for (int i = t; i < 8 * BW; i += 512) (&cnt8[0][0])[i] = 0;
  if (t < 10) biasS[t] = b1[t];
  __syncthreads();
  int cntb = bcnt[b];
  cntb = cntb > BCAP ? BCAP : cntb;
  const unsigned int* pp = pairs + (size_t)b * BCAP;
  for (int k = t; k < cntb; k += 512)
    atomicAdd(&cnt8[w][pp[k] & (BW - 1)], 1);
  __syncthreads();
  if (t < BW) {
    int tt = 0;
#pragma unroll
    for (int j = 0; j < 8; j++) tt += cnt8[j][t];
    tot[t] = tt;
    scanbuf[t] = tt;
  }
  __syncthreads();
  for (int step = 1; step < BW; step <<= 1) {  // Hillis-Steele inclusive scan
    int v = 0;
    if (t < BW && t >= step) v = scanbuf[t - step];
    __syncthreads();
    if (t < BW) scanbuf[t] += v;
    __syncthreads();
  }
  if (t < BW) {
    int run = scanbuf[t] - tot[t];
    offs[t] = run;
#pragma unroll
    for (int j = 0; j < 8; j++) { wb[j][t] = run; run += cnt8[j][t]; cnt8[j][t] = 0; }
  }
  __syncthreads();
  for (int k = t; k < cntb; k += 512) {
    unsigned int e = pp[k];
    int dl = e & (BW - 1);
    int pos = wb[w][dl] + atomicAdd(&cnt8[w][dl], 1);
    sorted[pos] = e >> BSH;
  }
  __syncthreads();
  // gather: node = t>>2 (adjacent lanes), part = t&3; shfl_xor combine
  int node = t >> 2;
  int part = t & 3;
  bool valid = node < nloc;
  int n = base_n + node;
  float acc[10];
#pragma unroll
  for (int j = 0; j < 10; j++) acc[j] = 0.f;
  float den0 = 0.f, den1 = 0.f;
  float2 adn = valid ? ad1[n] : make_float2(0.f, 0.f);
  int s0i = offs[node < BW ? node : 0], c = valid ? tot[node] : 0;
  for (int k = part; k < c; k += 4) {
    int s = (int)sorted[s0i + k];
    const float4* hs = (const float4*)(h1 + (size_t)s * 16);
    float4 r0 = hs[0], r1 = hs[1], r2 = hs[2];
    float e0 = r2.z + adn.x; e0 = e0 > 0.f ? e0 : 0.2f * e0;
    float e1 = r2.w + adn.y; e1 = e1 > 0.f ? e1 : 0.2f * e1;
    float x0 = expf(e0), x1 = expf(e1);
    acc[0] += x0 * r0.x;  acc[1] += x0 * r0.y;  acc[2] += x0 * r0.z;
    acc[3] += x0 * r0.w;  acc[4] += x0 * r1.x;
    acc[5] += x1 * r1.y;  acc[6] += x1 * r1.z;  acc[7] += x1 * r1.w;
    acc[8] += x1 * r2.x;  acc[9] += x1 * r2.y;
    den0 += x0; den1 += x1;
  }
#pragma unroll
  for (int j = 0; j < 10; j++) {
    acc[j] += __shfl_xor(acc[j], 1, 64);
    acc[j] += __shfl_xor(acc[j], 2, 64);
  }
  den0 += __shfl_xor(den0, 1, 64); den0 += __shfl_xor(den0, 2, 64);
  den1 += __shfl_xor(den1, 1, 64); den1 += __shfl_xor(den1, 2, 64);
  float v[10];
#pragma unroll
  for (int j = 0; j < 10; j++) v[j] = 0.f;
  if (part == 0 && valid) {
    // self-loop (src == dst == n)
    const float4* hs = (const float4*)(h1 + (size_t)n * 16);
    float4 r0 = hs[0], r1 = hs[1], r2 = hs[2];
    float e0 = r2.z + adn.x; e0 = e0 > 0.f ? e0 : 0.2f * e0;
    float e1 = r2.w + adn.y; e1 = e1 > 0.f ? e1 : 0.2f * e1;
    float x0 = expf(e0), x1 = expf(e1);
    acc[0] += x0 * r0.x;  acc[1] += x0 * r0.y;  acc[2] += x0 * r0.z;
    acc[3] += x0 * r0.w;  acc[4] += x0 * r1.x;
    acc[5] += x1 * r1.y;  acc[6] += x1 * r1.z;  acc[7] += x1 * r1.w;
    acc[8] += x1 * r2.x;  acc[9] += x1 * r2.y;
    den0 += x0; den1 += x1;
    float i0 = 1.f / (den0 + 1e-16f), i1 = 1.f / (den1 + 1e-16f);
#pragma unroll
    for (int j = 0; j < 5; j++) v[j] = acc[j] * i0 + biasS[j];
#pragma unroll
    for (int j = 5; j < 10; j++) v[j] = acc[j] * i1 + biasS[j];
    float4* gr = (float4*)(g1 + (size_t)n * 12);
    gr[0] = make_float4(v[0], v[1], v[2], v[3]);
    gr[1] = make_float4(v[4], v[5], v[6], v[7]);
    gr[2] = make_float4(v[8], v[9], 0.f, 0.f);
  }
  // BN partials: v is zero except part==0&&valid lanes; reduce per wave
  float s[20];
#pragma unroll
  for (int j = 0; j < 10; j++) { s[j] = v[j]; s[10 + j] = v[j] * v[j]; }
#pragma unroll
  for (int j = 0; j < 20; j++) {
    for (int off = 32; off > 0; off >>= 1) s[j] += __shfl_down(s[j], off, 64);
  }
  if ((t & 63) == 0) {
#pragma unroll
    for (int j = 0; j < 20; j++) bn_lds[w * 20 + j] = s[j];
  }
  __syncthreads();
  if (t == 0) {
#pragma unroll
    for (int j = 0; j < 20; j++) {
      float acc20 = 0.f;
#pragma unroll
      for (int ww = 0; ww < 8; ww++) acc20 += bn_lds[ww * 20 + j];
      bn_part[j * BNP + b] = acc20;  // unique slot, no atomic
    }
  }
}

// ---- BN final reduce: one block per channel-stat, no contended atomics -----
__global__ __launch_bounds__(64) void k_bnred(const float* __restrict__ bn_part,
                                              float* __restrict__ bns) {
  int j = blockIdx.x;  // 0..19
  int lane = threadIdx.x;
  float s = 0.f;
  for (int b = lane; b < NBKT; b += 64) s += bn_part[j * BNP + b];
#pragma unroll
  for (int off = 32; off > 0; off >>= 1) s += __shfl_down(s, off, 64);
  if (lane == 0) bns[j] = s;
}

// -------- Layer 2 node: BN + ELU + h2 = hn@W2; as2 embedded at r2.z ---------
__global__ __launch_bounds__(256) void k_l2_node(
    const float* __restrict__ g1, const float* __restrict__ bns,
    const float* __restrict__ gamma1, const float* __restrict__ beta1,
    const float* __restrict__ W2, const float* __restrict__ a_src2,
    const float* __restrict__ a_dst2, float* __restrict__ h2,
    float* __restrict__ ad2) {
  __shared__ float scale[10], shift[10], W2s[100], a2s[10], a2d[10];
  if (threadIdx.x < 10) {
    int j = threadIdx.x;
    float mu = bns[j] * (1.f / NN);
    float var = bns[10 + j] * (1.f / NN) - mu * mu;
    float rs = rsqrtf(var + 1e-5f);
    scale[j] = rs * gamma1[j];
    shift[j] = beta1[j] - mu * rs * gamma1[j];
    a2s[j] = a_src2[j];
    a2d[j] = a_dst2[j];
  }
  for (int i = threadIdx.x; i < 100; i += blockDim.x) W2s[i] = W2[i];
  __syncthreads();
  int n = blockIdx.x * blockDim.x + threadIdx.x;
  if (n >= NN) return;
  const float4* gr = (const float4*)(g1 + (size_t)n * 12);
  float4 g0 = gr[0], g1v = gr[1], g2 = gr[2];
  float hv[10] = {g0.x, g0.y, g0.z, g0.w, g1v.x, g1v.y, g1v.z, g1v.w, g2.x, g2.y};
#pragma unroll
  for (int j = 0; j < 10; j++) {
    float t = hv[j] * scale[j] + shift[j];
    hv[j] = t > 0.f ? t : expm1f(t);  // ELU
  }
  float o[10];
#pragma unroll
  for (int k = 0; k < 10; k++) o[k] = 0.f;
#pragma unroll
  for (int c = 0; c < 10; c++) {
#pragma unroll
    for (int k = 0; k < 10; k++) o[k] += hv[c] * W2s[c * 10 + k];
  }
  float ss = 0.f, sd = 0.f;
#pragma unroll
  for (int k = 0; k < 10; k++) { ss += o[k] * a2s[k]; sd += o[k] * a2d[k]; }
  float4* hr = (float4*)(h2 + (size_t)n * 16);
  hr[0] = make_float4(o[0], o[1], o[2], o[3]);
  hr[1] = make_float4(o[4], o[5], o[6], o[7]);
  hr[2] = make_float4(o[8], o[9], ss, 0.f);
  ad2[n] = sd;
}

// ---- L2 agg: same structure, 1 head, writes final out ----------------------
__global__ __launch_bounds__(512, 6) void k_l2_aggs(
    const int* __restrict__ bcnt, const unsigned int* __restrict__ pairs,
    const float* __restrict__ h2, const float* __restrict__ ad2,
    const float* __restrict__ b2, float* __restrict__ out) {
  __shared__ int cnt8[8][BW];
  __shared__ int wb[8][BW];
  __shared__ int offs[BW];
  __shared__ int tot[BW];
  __shared__ int scanbuf[BW];
  __shared__ unsigned int sorted[BCAP];
  __shared__ float biasS[10];
  int t = threadIdx.x;
  int w = t >> 6;
  int b = blockIdx.x;
  int base_n = b << BSH;
  int nloc = NN - base_n < BW ? NN - base_n : BW;
  for (int i = t; i < 8 * BW; i += 512) (&cnt8[0][0])[i] = 0;
  if (t < 10) biasS[t] = b2[t];
  __syncthreads();
  int cntb = bcnt[b];
  cntb = cntb > BCAP ? BCAP : cntb;
  const unsigned int* pp = pairs + (size_t)b * BCAP;
  for (int k = t; k < cntb; k += 512)
    atomicAdd(&cnt8[w][pp[k] & (BW - 1)], 1);
  __syncthreads();
  if (t < BW) {
    int tt = 0;
#pragma unroll
    for (int j = 0; j < 8; j++) tt += cnt8[j][t];
    tot[t] = tt;
    scanbuf[t] = tt;
  }
  __syncthreads();
  for (int step = 1; step < BW; step <<= 1) {
    int v = 0;
    if (t < BW && t >= step) v = scanbuf[t - step];
    __syncthreads();
    if (t < BW) scanbuf[t] += v;
    __syncthreads();
  }
  if (t < BW) {
    int run = scanbuf[t] - tot[t];
    offs[t] = run;
#pragma unroll
    for (int j = 0; j < 8; j++) { wb[j][t] = run; run += cnt8[j][t]; cnt8[j][t] = 0; }
  }
  __syncthreads();
  for (int k = t; k < cntb; k += 512) {
    unsigned int e = pp[k];
    int dl = e & (BW - 1);
    int pos = wb[w][dl] + atomicAdd(&cnt8[w][dl], 1);
    sorted[pos] = e >> BSH;
  }
  __syncthreads();
  int node = t >> 2;
  int part = t & 3;
  bool valid = node < nloc;
  int n = base_n + node;
  float acc[10];
#pragma unroll
  for (int j = 0; j < 10; j++) acc[j] = 0.f;
  float den = 0.f;
  float adn = valid ? ad2[n] : 0.f;
  int s0i = offs[node < BW ? node : 0], c = valid ? tot[node] : 0;
  for (int k = part; k < c; k += 4) {
    int s = (int)sorted[s0i + k];
    const float4* hs = (const float4*)(h2 + (size_t)s * 16);
    float4 r0 = hs[0], r1 = hs[1], r2 = hs[2];
    float ee = r2.z + adn; ee = ee > 0.f ? ee : 0.2f * ee;
    float xv = expf(ee);
    acc[0] += xv * r0.x;  acc[1] += xv * r0.y;  acc[2] += xv * r0.z;
    acc[3] += xv * r0.w;  acc[4] += xv * r1.x;  acc[5] += xv * r1.y;
    acc[6] += xv * r1.z;  acc[7] += xv * r1.w;  acc[8] += xv * r2.x;
    acc[9] += xv * r2.y;
    den += xv;
  }
#pragma unroll
  for (int j = 0; j < 10; j++) {
    acc[j] += __shfl_xor(acc[j], 1, 64);
    acc[j] += __shfl_xor(acc[j], 2, 64);
  }
  den += __shfl_xor(den, 1, 64); den += __shfl_xor(den, 2, 64);
  if (part == 0 && valid) {
    const float4* hs = (const float4*)(h2 + (size_t)n * 16);  // self-loop
    float4 r0 = hs[0], r1 = hs[1], r2 = hs[2];
    float ee = r2.z + adn; ee = ee > 0.f ? ee : 0.2f * ee;
    float xv = expf(ee);
    acc[0] += xv * r0.x;  acc[1] += xv * r0.y;  acc[2] += xv * r0.z;
    acc[3] += xv * r0.w;  acc[4] += xv * r1.x;  acc[5] += xv * r1.y;
    acc[6] += xv * r1.z;  acc[7] += xv * r1.w;  acc[8] += xv * r2.x;
    acc[9] += xv * r2.y;
    den += xv;
    float inv = 1.f / (den + 1e-16f);
    float2* orow = (float2*)(out + (size_t)n * 10);
    orow[0] = make_float2(acc[0] * inv + biasS[0], acc[1] * inv + biasS[1]);
    orow[1] = make_float2(acc[2] * inv + biasS[2], acc[3] * inv + biasS[3]);
    orow[2] = make_float2(acc[4] * inv + biasS[4], acc[5] * inv + biasS[5]);
    orow[3] = make_float2(acc[6] * inv + biasS[6], acc[7] * inv + biasS[7]);
    orow[4] = make_float2(acc[8] * inv + biasS[8], acc[9] * inv + biasS[9]);
  }
}

extern "C" void kernel_launch(void* const* d_in, const int* in_sizes, int n_in,
                              void* d_out, int out_size, void* d_ws, size_t ws_size,
                              hipStream_t stream) {
  const float* x      = (const float*)d_in[0];
  const float* W1     = (const float*)d_in[1];
  const float* a_src1 = (const float*)d_in[2];
  const float* a_dst1 = (const float*)d_in[3];
  const float* b1     = (const float*)d_in[4];
  const float* gamma1 = (const float*)d_in[5];
  const float* beta1  = (const float*)d_in[6];
  const float* W2     = (const float*)d_in[7];
  const float* a_src2 = (const float*)d_in[8];
  const float* a_dst2 = (const float*)d_in[9];
  const float* b2     = (const float*)d_in[10];
  const int*   ei     = (const int*)d_in[11];
  float* out = (float*)d_out;

  // Workspace layout (4B units), ~52.7 MB total (72 MB proven available).
  // All regions fully written before read -> no memset needed.
  int* bcnt = (int*)d_ws;                               // NBKT (k_scanb writes)
  unsigned int* pairs = (unsigned int*)d_ws + 1024;     // NBKT*BCAP
  float* h1 = (float*)(pairs + (size_t)NBKT * BCAP);    // NN*16
  float* ad1 = h1 + (size_t)NN * 16;                    // NN*2
  float* g1 = ad1 + (size_t)NN * 2;                     // NN*12
  float* h2 = g1 + (size_t)NN * 12;                     // NN*16
  float* ad2 = h2 + (size_t)NN * 16;                    // NN
  float* bn_part = ad2 + NN;                            // 20*BNP
  float* bns = bn_part + 20 * BNP;                      // 20
  int* cntmat = (int*)(bns + 20 + 12);                  // NBKT*NBP
  int* basemat = cntmat + (size_t)NBKT * NBP;           // NBKT*NBP

  const int B = 256;
  const int gN = (NN + B - 1) / B;               // 391
  const int gBin = (NE + BIN_CH - 1) / BIN_CH;   // 782

  k_count<<<gBin, B, 0, stream>>>(ei, cntmat);
  k_scanb<<<NBKT, 64, 0, stream>>>(cntmat, basemat, bcnt);
  k_scatter2<<<gBin, B, 0, stream>>>(ei, cntmat, basemat, pairs);
  k_l1_node<<<gN, B, 0, stream>>>(x, W1, a_src1, a_dst1, h1, (float2*)ad1);
  k_l1_aggs<<<NBKT, 512, 0, stream>>>(bcnt, pairs, h1, (const float2*)ad1, b1,
                                      g1, bn_part);
  k_bnred<<<20, 64, 0, stream>>>(bn_part, bns);
  k_l2_node<<<gN, B, 0, stream>>>(g1, bns, gamma1, beta1, W2, a_src2, a_dst2,
                                  h2, ad2);
  k_l2_aggs<<<NBKT, 512, 0, stream>>>(bcnt, pairs, h2, ad2, b2, out);
}

// Round 10
// 364.737 us; speedup vs baseline: 4.3831x; 1.1248x over previous
//
#include <hip/hip_runtime.h>
#include <hip/hip_fp16.h>
#include <math.h>

#define NN 100000
#define NE 6400000
#define INCH 128
#define BSH 7                       // bucket = 128 dst nodes
#define BW (1 << BSH)
#define NBKT ((NN + BW - 1) / BW)   // 782
#define NBP 784                     // padded row stride for cntmat/basemat
#define BCAP 9216                   // slots/bucket (mean 8192, +11 sigma)
#define BIN_CH 8192                 // edges per bin block
#define BNP 800                     // bn_part column stride (>= NBKT)

// fp16 pack/unpack helpers (h rows stored as 10xfp16 + fp32 logits, 32 B)
__device__ inline float pkh(float a, float b) {
  __half2 h = __floats2half2_rn(a, b);
  return __uint_as_float(*reinterpret_cast<unsigned int*>(&h));
}
__device__ inline float2 uph(float f) {
  unsigned int b = __float_as_uint(f);
  __half2 h = *reinterpret_cast<__half2*>(&b);
  return __half22float2(h);
}

// ---- Phase 1: per-chunk bucket histogram -> dense cntmat (no atomics) ------
__global__ __launch_bounds__(256) void k_count(const int* __restrict__ ei,
                                               int* __restrict__ cntmat) {
  __shared__ int cnt4[4][NBKT];
  int t = threadIdx.x;
  int w = t >> 6;
  for (int i = t; i < 4 * NBKT; i += 256) (&cnt4[0][0])[i] = 0;
  __syncthreads();
  int c0 = blockIdx.x * BIN_CH;
  int c1 = c0 + BIN_CH < NE ? c0 + BIN_CH : NE;
  for (int i = c0 + t; i < c1; i += 256)
    atomicAdd(&cnt4[w][ei[NE + i] >> BSH], 1);
  __syncthreads();
  for (int b = t; b < NBKT; b += 256)
    cntmat[(size_t)b * NBP + blockIdx.x] =
        cnt4[0][b] + cnt4[1][b] + cnt4[2][b] + cnt4[3][b];
}

// ---- Phase 2: per-bucket prefix over chunks (wave scan, no atomics) --------
__global__ __launch_bounds__(64) void k_scanb(const int* __restrict__ cntmat,
                                              int* __restrict__ basemat,
                                              int* __restrict__ bcnt) {
  int j = blockIdx.x;  // bucket
  int lane = threadIdx.x;
  int carry = 0;
  for (int i0 = 0; i0 < NBKT; i0 += 64) {
    int i = i0 + lane;
    int v0 = (i < NBKT) ? cntmat[(size_t)j * NBP + i] : 0;
    int v = v0;
#pragma unroll
    for (int off = 1; off < 64; off <<= 1) {
      int u = __shfl_up(v, off, 64);
      if (lane >= off) v += u;
    }
    if (i < NBKT) basemat[(size_t)i * NBP + j] = carry + v - v0;  // exclusive
    carry += __shfl(v, 63, 64);  // chunk total, uniform
  }
  if (lane == 0) bcnt[j] = carry;
}

// ---- Phase 3: LDS-staged counting sort; hist read from cntmat; no search ---
// Entry packing: (src << 7) | (dst & 127)  -- 24 bits used.
__global__ __launch_bounds__(256) void k_scatter2(
    const int* __restrict__ ei, const int* __restrict__ cntmat,
    const int* __restrict__ basemat, unsigned int* __restrict__ pairs) {
  __shared__ int offs[NBKT];           // staging exclusive offsets
  __shared__ int cur[NBKT];            // shared cursors (low contention)
  __shared__ int gbase[NBKT];          // global base per bucket (precomputed)
  __shared__ int scanp[256];
  __shared__ unsigned int stage[BIN_CH];
  __shared__ unsigned short sbkt[BIN_CH];  // bucket id per staged entry
  int t = threadIdx.x;
  int chunk = blockIdx.x;
  int myb0 = t * 4;
  int tots[4];
  int asum = 0;
#pragma unroll
  for (int j = 0; j < 4; j++) {
    int b = myb0 + j;
    int tt = (b < NBKT) ? cntmat[(size_t)b * NBP + chunk] : 0;
    tots[j] = tt;
    asum += tt;
  }
  for (int b = t; b < NBKT; b += 256)
    gbase[b] = basemat[(size_t)chunk * NBP + b];
  scanp[t] = asum;
  __syncthreads();
  for (int off = 1; off < 256; off <<= 1) {
    int v = (t >= off) ? scanp[t - off] : 0;
    __syncthreads();
    scanp[t] += v;
    __syncthreads();
  }
  int run = (t == 0) ? 0 : scanp[t - 1];
#pragma unroll
  for (int j = 0; j < 4; j++) {
    int b = myb0 + j;
    if (b < NBKT) {
      offs[b] = run;
      cur[b] = run;
      run += tots[j];
    }
  }
  __syncthreads();
  int c0 = chunk * BIN_CH;
  int c1 = c0 + BIN_CH < NE ? c0 + BIN_CH : NE;
  for (int i = c0 + t; i < c1; i += 256) {
    int s = ei[i], d = ei[NE + i];
    int bkt = d >> BSH;
    int pos = atomicAdd(&cur[bkt], 1);
    stage[pos] = ((unsigned int)s << BSH) | (unsigned int)(d & (BW - 1));
    sbkt[pos] = (unsigned short)bkt;
  }
  __syncthreads();
  int total = c1 - c0;
  for (int i = t; i < total; i += 256) {
    unsigned int e = stage[i];
    int b = sbkt[i];
    int gp = gbase[b] + (i - offs[b]);
    if (gp < BCAP) pairs[(size_t)b * BCAP + gp] = e;
  }
}

// ---------------- Layer 1 node: h1 = x@W1 -> fp16 row; logits fp32 ----------
// h1 row (8 dwords = 32 B): [h01,h23,h45,h67,h89 packed fp16, pad, asx, asy]
__global__ __launch_bounds__(256) void k_l1_node(
    const float* __restrict__ x, const float* __restrict__ W1,
    const float* __restrict__ a_src1, const float* __restrict__ a_dst1,
    float* __restrict__ h1, float2* __restrict__ ad1) {
  __shared__ float Wt[10 * INCH];
  __shared__ float asw[10], adw[10];
  for (int i = threadIdx.x; i < 10 * INCH; i += blockDim.x) {
    int c = i / 10, k = i - c * 10;
    Wt[k * INCH + c] = W1[i];
  }
  if (threadIdx.x < 10) {
    asw[threadIdx.x] = a_src1[threadIdx.x];
    adw[threadIdx.x] = a_dst1[threadIdx.x];
  }
  __syncthreads();
  int n = blockIdx.x * blockDim.x + threadIdx.x;
  if (n >= NN) return;
  const float4* xr = (const float4*)(x + (size_t)n * INCH);
  const float4* Wt4 = (const float4*)Wt;
  float acc[10];
#pragma unroll
  for (int k = 0; k < 10; k++) acc[k] = 0.f;
#pragma unroll 8
  for (int c4 = 0; c4 < INCH / 4; c4++) {
    float4 xv = xr[c4];
#pragma unroll
    for (int k = 0; k < 10; k++) {
      float4 wv = Wt4[k * (INCH / 4) + c4];
      acc[k] += xv.x * wv.x + xv.y * wv.y + xv.z * wv.z + xv.w * wv.w;
    }
  }
  float s0 = 0.f, s1 = 0.f, d0 = 0.f, d1 = 0.f;
#pragma unroll
  for (int j = 0; j < 5; j++) {
    s0 += acc[j] * asw[j];
    s1 += acc[5 + j] * asw[5 + j];
    d0 += acc[j] * adw[j];
    d1 += acc[5 + j] * adw[5 + j];
  }
  float4* hrow = (float4*)(h1 + (size_t)n * 8);
  hrow[0] = make_float4(pkh(acc[0], acc[1]), pkh(acc[2], acc[3]),
                        pkh(acc[4], acc[5]), pkh(acc[6], acc[7]));
  hrow[1] = make_float4(pkh(acc[8], acc[9]), 0.f, s0, s1);
  ad1[n] = make_float2(d0, d1);
}

// ---- L1 agg: LDS counting sort; 4 adjacent lanes/node; fp16 gather ---------
__global__ __launch_bounds__(512, 6) void k_l1_aggs(
    const int* __restrict__ bcnt, const unsigned int* __restrict__ pairs,
    const float* __restrict__ h1, const float2* __restrict__ ad1,
    const float* __restrict__ b1, float* __restrict__ g1,
    float* __restrict__ bn_part) {
  __shared__ int cnt8[8][BW];        // per-wave counts / cursors
  __shared__ int wb[8][BW];          // per-wave scatter base
  __shared__ int offs[BW];
  __shared__ int tot[BW];
  __shared__ int scanbuf[BW];
  __shared__ unsigned int sorted[BCAP];
  __shared__ float biasS[10];
  __shared__ float bn_lds[8 * 20];
  int t = threadIdx.x;
  int w = t >> 6;
  int b = blockIdx.x;
  int base_n = b << BSH;
  int nloc = NN - base_n < BW ? NN - base_n : BW;
  for (int i = t; i < 8 * BW; i += 512) (&cnt8[0][0])[i] = 0;
  if (t < 10) biasS[t] = b1[t];
  __syncthreads();
  int cntb = bcnt[b];
  cntb = cntb > BCAP ? BCAP : cntb;
  const unsigned int* pp = pairs + (size_t)b * BCAP;
  for (int k = t; k < cntb; k += 512)
    atomicAdd(&cnt8[w][pp[k] & (BW - 1)], 1);
  __syncthreads();
  if (t < BW) {
    int tt = 0;
#pragma unroll
    for (int j = 0; j < 8; j++) tt += cnt8[j][t];
    tot[t] = tt;
    scanbuf[t] = tt;
  }
  __syncthreads();
  for (int step = 1; step < BW; step <<= 1) {  // Hillis-Steele inclusive scan
    int v = 0;
    if (t < BW && t >= step) v = scanbuf[t - step];
    __syncthreads();
    if (t < BW) scanbuf[t] += v;
    __syncthreads();
  }
  if (t < BW) {
    int run = scanbuf[t] - tot[t];
    offs[t] = run;
#pragma unroll
    for (int j = 0; j < 8; j++) { wb[j][t] = run; run += cnt8[j][t]; cnt8[j][t] = 0; }
  }
  __syncthreads();
  for (int k = t; k < cntb; k += 512) {
    unsigned int e = pp[k];
    int dl = e & (BW - 1);
    int pos = wb[w][dl] + atomicAdd(&cnt8[w][dl], 1);
    sorted[pos] = e >> BSH;
  }
  __syncthreads();
  // gather: node = t>>2 (adjacent lanes), part = t&3; shfl_xor combine
  int node = t >> 2;
  int part = t & 3;
  bool valid = node < nloc;
  int n = base_n + node;
  float acc[10];
#pragma unroll
  for (int j = 0; j < 10; j++) acc[j] = 0.f;
  float den0 = 0.f, den1 = 0.f;
  float2 adn = valid ? ad1[n] : make_float2(0.f, 0.f);
  int s0i = offs[node], c = valid ? tot[node] : 0;
  for (int k = part; k < c; k += 4) {
    int s = (int)sorted[s0i + k];
    const float4* hs = (const float4*)(h1 + (size_t)s * 8);
    float4 ra = hs[0], rb = hs[1];
    float e0 = rb.z + adn.x; e0 = e0 > 0.f ? e0 : 0.2f * e0;
    float e1 = rb.w + adn.y; e1 = e1 > 0.f ? e1 : 0.2f * e1;
    float x0 = expf(e0), x1 = expf(e1);
    float2 h01 = uph(ra.x), h23 = uph(ra.y), h45 = uph(ra.z), h67 = uph(ra.w),
           h89 = uph(rb.x);
    acc[0] += x0 * h01.x;  acc[1] += x0 * h01.y;  acc[2] += x0 * h23.x;
    acc[3] += x0 * h23.y;  acc[4] += x0 * h45.x;
    acc[5] += x1 * h45.y;  acc[6] += x1 * h67.x;  acc[7] += x1 * h67.y;
    acc[8] += x1 * h89.x;  acc[9] += x1 * h89.y;
    den0 += x0; den1 += x1;
  }
#pragma unroll
  for (int j = 0; j < 10; j++) {
    acc[j] += __shfl_xor(acc[j], 1, 64);
    acc[j] += __shfl_xor(acc[j], 2, 64);
  }
  den0 += __shfl_xor(den0, 1, 64); den0 += __shfl_xor(den0, 2, 64);
  den1 += __shfl_xor(den1, 1, 64); den1 += __shfl_xor(den1, 2, 64);
  float v[10];
#pragma unroll
  for (int j = 0; j < 10; j++) v[j] = 0.f;
  if (part == 0 && valid) {
    // self-loop (src == dst == n)
    const float4* hs = (const float4*)(h1 + (size_t)n * 8);
    float4 ra = hs[0], rb = hs[1];
    float e0 = rb.z + adn.x; e0 = e0 > 0.f ? e0 : 0.2f * e0;
    float e1 = rb.w + adn.y; e1 = e1 > 0.f ? e1 : 0.2f * e1;
    float x0 = expf(e0), x1 = expf(e1);
    float2 h01 = uph(ra.x), h23 = uph(ra.y), h45 = uph(ra.z), h67 = uph(ra.w),
           h89 = uph(rb.x);
    acc[0] += x0 * h01.x;  acc[1] += x0 * h01.y;  acc[2] += x0 * h23.x;
    acc[3] += x0 * h23.y;  acc[4] += x0 * h45.x;
    acc[5] += x1 * h45.y;  acc[6] += x1 * h67.x;  acc[7] += x1 * h67.y;
    acc[8] += x1 * h89.x;  acc[9] += x1 * h89.y;
    den0 += x0; den1 += x1;
    float i0 = 1.f / (den0 + 1e-16f), i1 = 1.f / (den1 + 1e-16f);
#pragma unroll
    for (int j = 0; j < 5; j++) v[j] = acc[j] * i0 + biasS[j];
#pragma unroll
    for (int j = 5; j < 10; j++) v[j] = acc[j] * i1 + biasS[j];
    float4* gr = (float4*)(g1 + (size_t)n * 12);
    gr[0] = make_float4(v[0], v[1], v[2], v[3]);
    gr[1] = make_float4(v[4], v[5], v[6], v[7]);
    gr[2] = make_float4(v[8], v[9], 0.f, 0.f);
  }
  // BN partials: v is zero except part==0&&valid lanes; reduce per wave
  float s[20];
#pragma unroll
  for (int j = 0; j < 10; j++) { s[j] = v[j]; s[10 + j] = v[j] * v[j]; }
#pragma unroll
  for (int j = 0; j < 20; j++) {
    for (int off = 32; off > 0; off >>= 1) s[j] += __shfl_down(s[j], off, 64);
  }
  if ((t & 63) == 0) {
#pragma unroll
    for (int j = 0; j < 20; j++) bn_lds[w * 20 + j] = s[j];
  }
  __syncthreads();
  if (t == 0) {
#pragma unroll
    for (int j = 0; j < 20; j++) {
      float acc20 = 0.f;
#pragma unroll
      for (int ww = 0; ww < 8; ww++) acc20 += bn_lds[ww * 20 + j];
      bn_part[j * BNP + b] = acc20;  // unique slot, no atomic
    }
  }
}

// ---- BN final reduce: one block per channel-stat, no contended atomics -----
__global__ __launch_bounds__(64) void k_bnred(const float* __restrict__ bn_part,
                                              float* __restrict__ bns) {
  int j = blockIdx.x;  // 0..19
  int lane = threadIdx.x;
  float s = 0.f;
  for (int b = lane; b < NBKT; b += 64) s += bn_part[j * BNP + b];
#pragma unroll
  for (int off = 32; off > 0; off >>= 1) s += __shfl_down(s, off, 64);
  if (lane == 0) bns[j] = s;
}

// -------- Layer 2 node: BN + ELU + h2 = hn@W2 -> fp16 row; as2 fp32 ---------
// h2 row (8 dwords): [o01,o23,o45,o67,o89 packed fp16, pad, ss, pad]
__global__ __launch_bounds__(256) void k_l2_node(
    const float* __restrict__ g1, const float* __restrict__ bns,
    const float* __restrict__ gamma1, const float* __restrict__ beta1,
    const float* __restrict__ W2, const float* __restrict__ a_src2,
    const float* __restrict__ a_dst2, float* __restrict__ h2,
    float* __restrict__ ad2) {
  __shared__ float scale[10], shift[10], W2s[100], a2s[10], a2d[10];
  if (threadIdx.x < 10) {
    int j = threadIdx.x;
    float mu = bns[j] * (1.f / NN);
    float var = bns[10 + j] * (1.f / NN) - mu * mu;
    float rs = rsqrtf(var + 1e-5f);
    scale[j] = rs * gamma1[j];
    shift[j] = beta1[j] - mu * rs * gamma1[j];
    a2s[j] = a_src2[j];
    a2d[j] = a_dst2[j];
  }
  for (int i = threadIdx.x; i < 100; i += blockDim.x) W2s[i] = W2[i];
  __syncthreads();
  int n = blockIdx.x * blockDim.x + threadIdx.x;
  if (n >= NN) return;
  const float4* gr = (const float4*)(g1 + (size_t)n * 12);
  float4 g0 = gr[0], g1v = gr[1], g2 = gr[2];
  float hv[10] = {g0.x, g0.y, g0.z, g0.w, g1v.x, g1v.y, g1v.z, g1v.w, g2.x, g2.y};
#pragma unroll
  for (int j = 0; j < 10; j++) {
    float t = hv[j] * scale[j] + shift[j];
    hv[j] = t > 0.f ? t : expm1f(t);  // ELU
  }
  float o[10];
#pragma unroll
  for (int k = 0; k < 10; k++) o[k] = 0.f;
#pragma unroll
  for (int c = 0; c < 10; c++) {
#pragma unroll
    for (int k = 0; k < 10; k++) o[k] += hv[c] * W2s[c * 10 + k];
  }
  float ss = 0.f, sd = 0.f;
#pragma unroll
  for (int k = 0; k < 10; k++) { ss += o[k] * a2s[k]; sd += o[k] * a2d[k]; }
  float4* hr = (float4*)(h2 + (size_t)n * 8);
  hr[0] = make_float4(pkh(o[0], o[1]), pkh(o[2], o[3]), pkh(o[4], o[5]),
                      pkh(o[6], o[7]));
  hr[1] = make_float4(pkh(o[8], o[9]), 0.f, ss, 0.f);
  ad2[n] = sd;
}

// ---- L2 agg: same structure, 1 head, fp16 gather, writes final out ---------
__global__ __launch_bounds__(512, 6) void k_l2_aggs(
    const int* __restrict__ bcnt, const unsigned int* __restrict__ pairs,
    const float* __restrict__ h2, const float* __restrict__ ad2,
    const float* __restrict__ b2, float* __restrict__ out) {
  __shared__ int cnt8[8][BW];
  __shared__ int wb[8][BW];
  __shared__ int offs[BW];
  __shared__ int tot[BW];
  __shared__ int scanbuf[BW];
  __shared__ unsigned int sorted[BCAP];
  __shared__ float biasS[10];
  int t = threadIdx.x;
  int w = t >> 6;
  int b = blockIdx.x;
  int base_n = b << BSH;
  int nloc = NN - base_n < BW ? NN - base_n : BW;
  for (int i = t; i < 8 * BW; i += 512) (&cnt8[0][0])[i] = 0;
  if (t < 10) biasS[t] = b2[t];
  __syncthreads();
  int cntb = bcnt[b];
  cntb = cntb > BCAP ? BCAP : cntb;
  const unsigned int* pp = pairs + (size_t)b * BCAP;
  for (int k = t; k < cntb; k += 512)
    atomicAdd(&cnt8[w][pp[k] & (BW - 1)], 1);
  __syncthreads();
  if (t < BW) {
    int tt = 0;
#pragma unroll
    for (int j = 0; j < 8; j++) tt += cnt8[j][t];
    tot[t] = tt;
    scanbuf[t] = tt;
  }
  __syncthreads();
  for (int step = 1; step < BW; step <<= 1) {
    int v = 0;
    if (t < BW && t >= step) v = scanbuf[t - step];
    __syncthreads();
    if (t < BW) scanbuf[t] += v;
    __syncthreads();
  }
  if (t < BW) {
    int run = scanbuf[t] - tot[t];
    offs[t] = run;
#pragma unroll
    for (int j = 0; j < 8; j++) { wb[j][t] = run; run += cnt8[j][t]; cnt8[j][t] = 0; }
  }
  __syncthreads();
  for (int k = t; k < cntb; k += 512) {
    unsigned int e = pp[k];
    int dl = e & (BW - 1);
    int pos = wb[w][dl] + atomicAdd(&cnt8[w][dl], 1);
    sorted[pos] = e >> BSH;
  }
  __syncthreads();
  int node = t >> 2;
  int part = t & 3;
  bool valid = node < nloc;
  int n = base_n + node;
  float acc[10];
#pragma unroll
  for (int j = 0; j < 10; j++) acc[j] = 0.f;
  float den = 0.f;
  float adn = valid ? ad2[n] : 0.f;
  int s0i = offs[node], c = valid ? tot[node] : 0;
  for (int k = part; k < c; k += 4) {
    int s = (int)sorted[s0i + k];
    const float4* hs = (const float4*)(h2 + (size_t)s * 8);
    float4 ra = hs[0], rb = hs[1];
    float ee = rb.z + adn; ee = ee > 0.f ? ee : 0.2f * ee;
    float xv = expf(ee);
    float2 h01 = uph(ra.x), h23 = uph(ra.y), h45 = uph(ra.z), h67 = uph(ra.w),
           h89 = uph(rb.x);
    acc[0] += xv * h01.x;  acc[1] += xv * h01.y;  acc[2] += xv * h23.x;
    acc[3] += xv * h23.y;  acc[4] += xv * h45.x;  acc[5] += xv * h45.y;
    acc[6] += xv * h67.x;  acc[7] += xv * h67.y;  acc[8] += xv * h89.x;
    acc[9] += xv * h89.y;
    den += xv;
  }
#pragma unroll
  for (int j = 0; j < 10; j++) {
    acc[j] += __shfl_xor(acc[j], 1, 64);
    acc[j] += __shfl_xor(acc[j], 2, 64);
  }
  den += __shfl_xor(den, 1, 64); den += __shfl_xor(den, 2, 64);
  if (part == 0 && valid) {
    const float4* hs = (const float4*)(h2 + (size_t)n * 8);  // self-loop
    float4 ra = hs[0], rb = hs[1];
    float ee = rb.z + adn; ee = ee > 0.f ? ee : 0.2f * ee;
    float xv = expf(ee);
    float2 h01 = uph(ra.x), h23 = uph(ra.y), h45 = uph(ra.z), h67 = uph(ra.w),
           h89 = uph(rb.x);
    acc[0] += xv * h01.x;  acc[1] += xv * h01.y;  acc[2] += xv * h23.x;
    acc[3] += xv * h23.y;  acc[4] += xv * h45.x;  acc[5] += xv * h45.y;
    acc[6] += xv * h67.x;  acc[7] += xv * h67.y;  acc[8] += xv * h89.x;
    acc[9] += xv * h89.y;
    den += xv;
    float inv = 1.f / (den + 1e-16f);
    float2* orow = (float2*)(out + (size_t)n * 10);
    orow[0] = make_float2(acc[0] * inv + biasS[0], acc[1] * inv + biasS[1]);
    orow[1] = make_float2(acc[2] * inv + biasS[2], acc[3] * inv + biasS[3]);
    orow[2] = make_float2(acc[4] * inv + biasS[4], acc[5] * inv + biasS[5]);
    orow[3] = make_float2(acc[6] * inv + biasS[6], acc[7] * inv + biasS[7]);
    orow[4] = make_float2(acc[8] * inv + biasS[8], acc[9] * inv + biasS[9]);
  }
}

extern "C" void kernel_launch(void* const* d_in, const int* in_sizes, int n_in,
                              void* d_out, int out_size, void* d_ws, size_t ws_size,
                              hipStream_t stream) {
  const float* x      = (const float*)d_in[0];
  const float* W1     = (const float*)d_in[1];
  const float* a_src1 = (const float*)d_in[2];
  const float* a_dst1 = (const float*)d_in[3];
  const float* b1     = (const float*)d_in[4];
  const float* gamma1 = (const float*)d_in[5];
  const float* beta1  = (const float*)d_in[6];
  const float* W2     = (const float*)d_in[7];
  const float* a_src2 = (const float*)d_in[8];
  const float* a_dst2 = (const float*)d_in[9];
  const float* b2     = (const float*)d_in[10];
  const int*   ei     = (const int*)d_in[11];
  float* out = (float*)d_out;

  // Workspace layout (4B units). All regions fully written before read.
  int* bcnt = (int*)d_ws;                               // NBKT (k_scanb writes)
  unsigned int* pairs = (unsigned int*)d_ws + 1024;     // NBKT*BCAP
  float* h1 = (float*)(pairs + (size_t)NBKT * BCAP);    // NN*8 (fp16 rows)
  float* ad1 = h1 + (size_t)NN * 8;                     // NN*2
  float* g1 = ad1 + (size_t)NN * 2;                     // NN*12
  float* h2 = g1 + (size_t)NN * 12;                     // NN*8 (fp16 rows)
  float* ad2 = h2 + (size_t)NN * 8;                     // NN
  float* bn_part = ad2 + NN;                            // 20*BNP
  float* bns = bn_part + 20 * BNP;                      // 20
  int* cntmat = (int*)(bns + 20 + 12);                  // NBKT*NBP
  int* basemat = cntmat + (size_t)NBKT * NBP;           // NBKT*NBP

  const int B = 256;
  const int gN = (NN + B - 1) / B;               // 391
  const int gBin = (NE + BIN_CH - 1) / BIN_CH;   // 782

  k_count<<<gBin, B, 0, stream>>>(ei, cntmat);
  k_scanb<<<NBKT, 64, 0, stream>>>(cntmat, basemat, bcnt);
  k_scatter2<<<gBin, B, 0, stream>>>(ei, cntmat, basemat, pairs);
  k_l1_node<<<gN, B, 0, stream>>>(x, W1, a_src1, a_dst1, h1, (float2*)ad1);
  k_l1_aggs<<<NBKT, 512, 0, stream>>>(bcnt, pairs, h1, (const float2*)ad1, b1,
                                      g1, bn_part);
  k_bnred<<<20, 64, 0, stream>>>(bn_part, bns);
  k_l2_node<<<gN, B, 0, stream>>>(g1, bns, gamma1, beta1, W2, a_src2, a_dst2,
                                  h2, ad2);
  k_l2_aggs<<<NBKT, 512, 0, stream>>>(bcnt, pairs, h2, ad2, b2, out);
}